// Round 7
// baseline (16985.629 us; speedup 1.0000x reference)
//
#include <hip/hip_runtime.h>

#define NSVC 2000
#define NPOD 8000
#define NNODE 1000
#define NTOT 11000
#define TT 32
#define FF 64
#define HH 128
#define EA 30000
#define EB 24000
#define EC 24000
#define ETOT (EA + EB + EC)
#define CHK 64
#define NCH ((NTOT + CHK - 1) / CHK)   // 172 (all chunk lengths even)

// ---------------- agent-scope helpers (cross-XCD safe) ----------------
__device__ __forceinline__ float ld_agent(const float* p) {
    return __hip_atomic_load(p, __ATOMIC_RELAXED, __HIP_MEMORY_SCOPE_AGENT);
}
__device__ __forceinline__ float2 ld_agent2(const float* p) {
    unsigned long long v = __hip_atomic_load((const unsigned long long*)p,
                                             __ATOMIC_RELAXED, __HIP_MEMORY_SCOPE_AGENT);
    union { unsigned long long u; float2 f; } cv; cv.u = v; return cv.f;
}
__device__ __forceinline__ void st_agent(float* p, float v) {
    __hip_atomic_store(p, v, __ATOMIC_RELAXED, __HIP_MEMORY_SCOPE_AGENT);
}
// barrier that does NOT drain vmcnt (keeps global loads/stores in flight)
__device__ __forceinline__ void bar_fast() {
    asm volatile("s_waitcnt lgkmcnt(0)" ::: "memory");
    __builtin_amdgcn_s_barrier();
}
// DPP quad_perm xor1 = 0xB1 [1,0,3,2]: swap within each lane pair.
template<int CTRL>
__device__ __forceinline__ float qperm(float x) {
    return __int_as_float(__builtin_amdgcn_mov_dpp(__float_as_int(x), CTRL, 0xF, 0xF, false));
}

// ---------------- merged degree counting ----------------
__global__ void k_count3(const int* __restrict__ sA, const int* __restrict__ dA,
                         const int* __restrict__ sB, const int* __restrict__ dB,
                         const int* __restrict__ sC, const int* __restrict__ dC,
                         float* ocA, float* icA, float* ocB, float* icB,
                         float* ocC, float* icC) {
    int e = blockIdx.x * 256 + threadIdx.x;
    if (e < EA) {
        atomicAdd(ocA + sA[e], 1.f); atomicAdd(icA + dA[e], 1.f);
    } else if (e < EA + EB) {
        int i = e - EA;
        atomicAdd(ocB + sB[i], 1.f); atomicAdd(icB + dB[i], 1.f);
    } else if (e < ETOT) {
        int i = e - EA - EB;
        atomicAdd(ocC + sC[i], 1.f); atomicAdd(icC + dC[i], 1.f);
    }
}

// ---------------- prefix scan (3 graphs, one block each) ----------------
__global__ void k_scan(const float* cA, int nA, int* oA,
                       const float* cB, int nB, int* oB,
                       const float* cC, int nC, int* oC) {
    const float* c; int n; int* o;
    if (blockIdx.x == 0)      { c = cA; n = nA; o = oA; }
    else if (blockIdx.x == 1) { c = cB; n = nB; o = oB; }
    else                      { c = cC; n = nC; o = oC; }
    __shared__ int s[256];
    __shared__ int carry;
    int tid = threadIdx.x;
    if (tid == 0) { carry = 0; o[0] = 0; }
    __syncthreads();
    for (int base = 0; base < n; base += 256) {
        int idx = base + tid;
        int v = (idx < n) ? (int)c[idx] : 0;
        s[tid] = v;
        __syncthreads();
        for (int d = 1; d < 256; d <<= 1) {
            int t = (tid >= d) ? s[tid - d] : 0;
            __syncthreads();
            s[tid] += t;
            __syncthreads();
        }
        if (idx < n) o[idx + 1] = carry + s[tid];
        __syncthreads();
        if (tid == 255) carry += s[255];
        __syncthreads();
    }
}

// ---------------- merged CSR scatter ----------------
__global__ void k_scatter3(const int* __restrict__ sA, const int* __restrict__ dA,
                           const int* __restrict__ sB, const int* __restrict__ dB,
                           const int* __restrict__ sC, const int* __restrict__ dC,
                           const int* offA, int* curA, int* csrA,
                           const int* offB, int* curB, int* csrB,
                           const int* offC, int* curC, int* csrC) {
    int e = blockIdx.x * 256 + threadIdx.x;
    if (e < EA) {
        int d = dA[e]; int p = atomicAdd(curA + d, 1); csrA[offA[d] + p] = sA[e];
    } else if (e < EA + EB) {
        int i = e - EA;
        int d = dB[i]; int p = atomicAdd(curB + d, 1); csrB[offB[d] + p] = sB[i];
    } else if (e < ETOT) {
        int i = e - EA - EB;
        int d = dC[i]; int p = atomicAdd(curC + d, 1); csrC[offC[d] + p] = sC[i];
    }
}

// ---------------- fused conv (3 graphs merged, 16 dst/block) ----------------
#define YA16 ((NSVC + 15) / 16)    // 125
#define YC16 ((NPOD + 15) / 16)    // 500
#define YB16 ((NNODE + 15) / 16)   // 63
__global__ __launch_bounds__(256) void k_conv3(
    const float* __restrict__ feat_svc, const float* __restrict__ feat_pod,
    const float* __restrict__ feat_node,
    const float* __restrict__ w_svc, const float* __restrict__ b_svc,
    const float* __restrict__ lw_svc, const float* __restrict__ lb_svc,
    const float* __restrict__ w_ni, const float* __restrict__ b_ni,
    const float* __restrict__ lw_pod, const float* __restrict__ lb_pod,
    const float* __restrict__ w_in, const float* __restrict__ b_in,
    const float* __restrict__ lw_node, const float* __restrict__ lb_node,
    const float* ocA, const float* icA, const int* offA, const int* csrA,
    const float* ocC, const float* icC, const int* offC, const int* csrC,
    const float* ocB, const float* icB, const int* offB, const int* csrB,
    float* __restrict__ xseq)
{
    __shared__ float wl[FF * HH];
    __shared__ float bl[HH], lwl[HH];
    __shared__ float accs[4][FF];
    const int t = blockIdx.x;
    const int tid = threadIdx.x;
    int yb = blockIdx.y;
    const float *x, *w, *b, *lw, *lb, *oc, *ic; const int *off, *csr;
    int Ndst, rowofs;
    if (yb < YA16) {
        x = feat_svc; w = w_svc; b = b_svc; lw = lw_svc; lb = lb_svc;
        oc = ocA; ic = icA; off = offA; csr = csrA; Ndst = NSVC; rowofs = 0;
    } else if (yb < YA16 + YC16) {
        yb -= YA16;
        x = feat_node; w = w_ni; b = b_ni; lw = lw_pod; lb = lb_pod;
        oc = ocC; ic = icC; off = offC; csr = csrC; Ndst = NPOD; rowofs = NSVC;
    } else {
        yb -= YA16 + YC16;
        x = feat_pod; w = w_in; b = b_in; lw = lw_node; lb = lb_node;
        oc = ocB; ic = icB; off = offB; csr = csrB; Ndst = NNODE; rowofs = NSVC + NPOD;
    }
    for (int i = tid; i < FF * HH; i += 256) wl[i] = w[t * FF * HH + i];
    if (tid < HH) { bl[tid] = b[t * HH + tid]; lwl[tid] = lw[t * HH + tid]; }
    const int wv = tid >> 6, lane = tid & 63;
    __syncthreads();
    for (int sub = 0; sub < 4; ++sub) {
        const int dstn = yb * 16 + sub * 4 + wv;
        if (dstn < Ndst) {
            float a = 0.f;
            const int e0 = off[dstn], e1 = off[dstn + 1];
            const float* xb = x + (size_t)t * FF + lane;
            float xsP = 0.f, ocP = 1.f;
            if (e0 < e1) {
                int s0 = csr[e0];
                xsP = xb[(size_t)s0 * (TT * FF)]; ocP = oc[s0];
            }
            for (int i = e0; i < e1; ++i) {
                float xs = xsP, od = ocP;
                if (i + 1 < e1) {
                    int s2 = csr[i + 1];
                    xsP = xb[(size_t)s2 * (TT * FF)]; ocP = oc[s2];
                }
                a = fmaf(xs, rsqrtf(fmaxf(od, 1.f)), a);
            }
            a *= rsqrtf(fmaxf(ic[dstn], 1.f));
            accs[wv][lane] = a;     // wave-local: write then read by same wave
            float h0 = bl[lane], h1v = bl[64 + lane];
            #pragma unroll
            for (int f = 0; f < FF; ++f) {
                float af = accs[wv][f];
                h0  = fmaf(af, wl[f * HH + lane], h0);
                h1v = fmaf(af, wl[f * HH + 64 + lane], h1v);
            }
            h0  = (h0  >= 0.f) ? h0  : 0.01f * h0;
            h1v = (h1v >= 0.f) ? h1v : 0.01f * h1v;
            float p = h0 * lwl[lane] + h1v * lwl[64 + lane];
            #pragma unroll
            for (int o2 = 32; o2 >= 1; o2 >>= 1) p += __shfl_down(p, o2);
            if (lane == 0) xseq[(size_t)(rowofs + dstn) * TT + t] = p + lb[t];
        }
    }
}

// X layout: gate-major row r = g*128+j is stored at column 4j + 2*(g&1) + (g>>1),
// so rec thread tid = 2j+p reads float2 at X[n*512 + 2*tid]:
//   .x = gate p (i or f), .y = gate 2+p (g or o). Coalesced 8B/lane.
__device__ __forceinline__ int xcol(int r) {
    int j = r & 127, g = r >> 7;
    return (j << 2) | ((g & 1) << 1) | (g >> 1);
}

// ---------------- input projection (layer 1): X = xin @ wih^T + (bih + bhh) --------
__global__ __launch_bounds__(256) void k_proj(
    const float* __restrict__ xin, int K,      // [N, K]
    const float* __restrict__ wih,             // [512, K]
    const float* __restrict__ bih, const float* __restrict__ bhh,
    float* __restrict__ Xout, int N)           // [N, 512] permuted cols
{
    __shared__ float xt[16 * 128];
    int n0 = blockIdx.x * 16, tid = threadIdx.x;
    for (int i = tid; i < 16 * K; i += 256) {
        int nn = i / K, kk = i - nn * K;
        int n = n0 + nn;
        xt[i] = (n < N) ? xin[(size_t)n * K + kk] : 0.f;
    }
    __syncthreads();
    float acc0[16], acc1[16];
    #pragma unroll
    for (int i = 0; i < 16; ++i) { acc0[i] = 0.f; acc1[i] = 0.f; }
    int r0 = tid, r1 = tid + 256;
    for (int k = 0; k < K; ++k) {
        float w0 = wih[(size_t)r0 * K + k];
        float w1 = wih[(size_t)r1 * K + k];
        #pragma unroll
        for (int i = 0; i < 16; ++i) {
            float xv = xt[i * K + k];
            acc0[i] = fmaf(xv, w0, acc0[i]);
            acc1[i] = fmaf(xv, w1, acc1[i]);
        }
    }
    float b0 = bih[r0] + bhh[r0], b1 = bih[r1] + bhh[r1];
    int c0 = xcol(r0), c1 = xcol(r1);
    for (int i = 0; i < 16; ++i) {
        int n = n0 + i;
        if (n < N) {
            Xout[(size_t)n * 512 + c0] = acc0[i] + b0;
            Xout[(size_t)n * 512 + c1] = acc1[i] + b1;
        }
    }
}

// ---------------- sequential LSTM recurrence (256 threads = 4 waves, 1/SIMD) -------
// thread = (j,p): unit j = tid>>1, k-half p = tid&1. Each thread holds w[4][64]
// = 256 VGPRs (1 wave/SIMD -> up to 512-VGPR budget: weights RESIDENT, no spill).
// h reads are half-wave-uniform LDS broadcasts. One DPP xor1 reduce -> lane p
// holds gates {p, p+2}; 2 activations/lane; one DPP swap; redundant c per pair.
__device__ void lstm_rec(const float* __restrict__ X, const float* __restrict__ Whh,
                         float* __restrict__ Hout, bool agent_x, bool agent_h,
                         int* wflagA, int* wflagB, int* sflag)
{
    __shared__ __align__(16) float hb0s[HH], hb1s[HH];
    const int tid = threadIdx.x;        // 0..255
    const int j = tid >> 1, p = tid & 1;
    // weights: gate g row (g*128+j), k-slice [p*64, p*64+64) -> 16 float4 per gate
    float4 w0[16], w1[16], w2[16], w3[16];
    {
        const float* base = Whh + (size_t)j * HH + p * 64;
        const float4* r0 = reinterpret_cast<const float4*>(base);
        const float4* r1 = reinterpret_cast<const float4*>(base + 128 * HH);
        const float4* r2 = reinterpret_cast<const float4*>(base + 256 * HH);
        const float4* r3 = reinterpret_cast<const float4*>(base + 384 * HH);
        #pragma unroll
        for (int q = 0; q < 16; ++q) { w0[q] = r0[q]; w1[q] = r1[q]; w2[q] = r2[q]; w3[q] = r3[q]; }
    }
    if (tid < HH) hb0s[tid] = 0.f;
    // v-activation: p==0 -> tanh (gate g): a = 1 - 2/(1+e^{2s}); p==1 -> sigmoid (gate o)
    const float k1v = (p == 0) ? -2.f : 1.f;
    const float k2v = (p == 0) ? 2.f : -1.f;
    const float k3v = (p == 0) ? 1.f : 0.f;
    float c = 0.f;   // identical across each lane pair
    __syncthreads();

    auto step = [&](const float* hsrc, float* hdst, float2 xc, float* ho) {
        const float4* hr = reinterpret_cast<const float4*>(hsrc + (p << 6));
        float s0 = 0.f, s1 = 0.f, s2 = 0.f, s3 = 0.f;
        #pragma unroll
        for (int q = 0; q < 16; ++q) {
            float4 h4 = hr[q];
            s0 = fmaf(w0[q].x, h4.x, s0); s0 = fmaf(w0[q].y, h4.y, s0);
            s0 = fmaf(w0[q].z, h4.z, s0); s0 = fmaf(w0[q].w, h4.w, s0);
            s1 = fmaf(w1[q].x, h4.x, s1); s1 = fmaf(w1[q].y, h4.y, s1);
            s1 = fmaf(w1[q].z, h4.z, s1); s1 = fmaf(w1[q].w, h4.w, s1);
            s2 = fmaf(w2[q].x, h4.x, s2); s2 = fmaf(w2[q].y, h4.y, s2);
            s2 = fmaf(w2[q].z, h4.z, s2); s2 = fmaf(w2[q].w, h4.w, s2);
            s3 = fmaf(w3[q].x, h4.x, s3); s3 = fmaf(w3[q].y, h4.y, s3);
            s3 = fmaf(w3[q].z, h4.z, s3); s3 = fmaf(w3[q].w, h4.w, s3);
        }
        // pair reduce-scatter (DPP xor1): lane p -> full sums of gates p and p+2
        float zA = p ? s0 : s1;
        float u  = (p ? s1 : s0) + qperm<0xB1>(zA);   // gate p   (i or f)
        float zB = p ? s2 : s3;
        float v  = (p ? s3 : s2) + qperm<0xB1>(zB);   // gate p+2 (g or o)
        u += xc.x; v += xc.y;
        // activations: u sigmoid on both lanes; v tanh(p=0)/sigmoid(p=1)
        float au = __builtin_amdgcn_rcpf(1.f + __expf(-u));
        float ev = __expf(k2v * v);
        float av = fmaf(k1v, __builtin_amdgcn_rcpf(1.f + ev), k3v);
        // pair swap: lane0 {a_i,a_g} <-> lane1 {a_f,a_o}
        float fu = qperm<0xB1>(au);   // lane0: a_f ; lane1: a_i
        float fv = qperm<0xB1>(av);   // lane0: a_o ; lane1: a_g
        float A_f = p ? au : fu;
        float A_i = p ? fu : au;
        float A_g = p ? fv : av;
        float A_o = p ? av : fv;
        c = fmaf(A_f, c, A_i * A_g);  // bit-identical across the pair
        float e2 = __expf(2.f * c);
        float th = fmaf(-2.f, __builtin_amdgcn_rcpf(1.f + e2), 1.f);
        float hnew = A_o * th;
        if (p == 0) {
            hdst[j] = hnew;
            if (agent_h) st_agent(ho, hnew); else *ho = hnew;
        }
        bar_fast();   // lgkmcnt only: global ops stay in flight
    };

    for (int ch = 0; ch < NCH; ++ch) {
        const int n0 = ch * CHK;
        const int n1 = (n0 + CHK < NTOT) ? (n0 + CHK) : NTOT;   // even count
        if (wflagA) {
            if (tid == 0) {
                while (__hip_atomic_load(wflagA + ch, __ATOMIC_RELAXED, __HIP_MEMORY_SCOPE_AGENT) == 0)
                    __builtin_amdgcn_s_sleep(1);
                if (wflagB) {
                    while (__hip_atomic_load(wflagB + ch, __ATOMIC_RELAXED, __HIP_MEMORY_SCOPE_AGENT) == 0)
                        __builtin_amdgcn_s_sleep(1);
                }
            }
            __syncthreads();
            __threadfence();   // acquire
        }
        const float* xb = X + 2 * tid;   // coalesced float2 (permuted layout)
        float2 xc0 = agent_x ? ld_agent2(xb + (size_t)n0 * 512)
                             : *reinterpret_cast<const float2*>(xb + (size_t)n0 * 512);
        float2 xc1 = agent_x ? ld_agent2(xb + (size_t)(n0 + 1) * 512)
                             : *reinterpret_cast<const float2*>(xb + (size_t)(n0 + 1) * 512);
        for (int n = n0; n < n1; n += 2) {
            float2 xp2 = {0.f, 0.f}, xp3 = {0.f, 0.f};
            if (n + 2 < n1) {
                const float* q2 = xb + (size_t)(n + 2) * 512;
                const float* q3 = xb + (size_t)(n + 3) * 512;
                xp2 = agent_x ? ld_agent2(q2) : *reinterpret_cast<const float2*>(q2);
                xp3 = agent_x ? ld_agent2(q3) : *reinterpret_cast<const float2*>(q3);
            }
            step(hb0s, hb1s, xc0, Hout + (size_t)n * HH + j);
            step(hb1s, hb0s, xc1, Hout + (size_t)(n + 1) * HH + j);
            xc0 = xp2; xc1 = xp3;
        }
        if (sflag) {
            __syncthreads();   // full drain: h stores visible before flag
            if (tid == 0)
                __hip_atomic_store(sflag + ch, 1, __ATOMIC_RELEASE, __HIP_MEMORY_SCOPE_AGENT);
        }
    }
}

// ---------------- layer-2 input projection worker (2 blocks x 256 rows) ----------
__device__ void proj_work(const float* __restrict__ h1, const float* __restrict__ Wih,
                          const float* __restrict__ bih, const float* __restrict__ bhh,
                          float* __restrict__ X2, int* wflag, int* sflag, int rowbase)
{
    __shared__ float hl[CHK * HH];     // 32 KB
    const int tid = threadIdx.x;       // 0..255
    const int r = rowbase + tid;       // gate-major row of W_ih1
    const float bsum = bih[r] + bhh[r];
    const int col = xcol(r);
    const float4* wr = reinterpret_cast<const float4*>(Wih + (size_t)r * HH);
    for (int ch = 0; ch < NCH; ++ch) {
        const int n0 = ch * CHK;
        const int cnt = (n0 + CHK < NTOT) ? CHK : (NTOT - n0);
        if (tid == 0) {
            while (__hip_atomic_load(wflag + ch, __ATOMIC_RELAXED, __HIP_MEMORY_SCOPE_AGENT) == 0)
                __builtin_amdgcn_s_sleep(1);
        }
        __syncthreads();
        __threadfence();
        for (int i = tid; i < cnt * HH; i += 256)
            hl[i] = ld_agent(h1 + (size_t)n0 * HH + i);
        __syncthreads();
        for (int t0 = 0; t0 < cnt; t0 += 16) {
            float acc[16];
            #pragma unroll
            for (int i = 0; i < 16; ++i) acc[i] = bsum;
            for (int k4 = 0; k4 < HH / 4; ++k4) {
                float4 wv = wr[k4];
                #pragma unroll
                for (int i = 0; i < 16; ++i) {
                    const float* hh = &hl[(t0 + i) * HH + 4 * k4];
                    acc[i] += wv.x*hh[0] + wv.y*hh[1] + wv.z*hh[2] + wv.w*hh[3];
                }
            }
            int tl = cnt - t0; if (tl > 16) tl = 16;
            for (int i = 0; i < tl; ++i)
                st_agent(X2 + (size_t)(n0 + t0 + i) * 512 + col, acc[i]);
        }
        __syncthreads();   // drain stores
        if (tid == 0)
            __hip_atomic_store(sflag + ch, 1, __ATOMIC_RELEASE, __HIP_MEMORY_SCOPE_AGENT);
    }
}

// ---------------- 4-stage pipeline: L1 rec | proj lo | proj hi | L2 rec ----------
// 256 threads/block, 1 wave/SIMD -> up to 512 VGPRs/wave: weights stay resident.
__global__ __launch_bounds__(256, 1) void k_pipe(
    const float* __restrict__ X1, const float* __restrict__ w_hh0, float* __restrict__ h1,
    const float* __restrict__ w_ih1, const float* __restrict__ b_ih1, const float* __restrict__ b_hh1,
    float* __restrict__ X2, const float* __restrict__ w_hh1, float* __restrict__ out,
    int* flags1, int* flags2a, int* flags2b)
{
    if (blockIdx.x == 0)
        lstm_rec(X1, w_hh0, h1, false, true, nullptr, nullptr, flags1);
    else if (blockIdx.x == 1)
        proj_work(h1, w_ih1, b_ih1, b_hh1, X2, flags1, flags2a, 0);
    else if (blockIdx.x == 2)
        proj_work(h1, w_ih1, b_ih1, b_hh1, X2, flags1, flags2b, 256);
    else
        lstm_rec(X2, w_hh1, out, true, false, flags2a, flags2b, nullptr);
}

extern "C" void kernel_launch(void* const* d_in, const int* in_sizes, int n_in,
                              void* d_out, int out_size, void* d_ws, size_t ws_size,
                              hipStream_t stream) {
    const float* feat_svc = (const float*)d_in[0];
    const float* feat_pod = (const float*)d_in[1];
    const float* feat_node= (const float*)d_in[2];
    const float* w_svc = (const float*)d_in[3];
    const float* b_svc = (const float*)d_in[4];
    const float* w_in  = (const float*)d_in[5];
    const float* b_in  = (const float*)d_in[6];
    const float* w_ni  = (const float*)d_in[7];
    const float* b_ni  = (const float*)d_in[8];
    const float* lw_svc = (const float*)d_in[9];
    const float* lb_svc = (const float*)d_in[10];
    const float* lw_pod = (const float*)d_in[11];
    const float* lb_pod = (const float*)d_in[12];
    const float* lw_node= (const float*)d_in[13];
    const float* lb_node= (const float*)d_in[14];
    const float* w_ih0 = (const float*)d_in[15];
    const float* w_hh0 = (const float*)d_in[16];
    const float* b_ih0 = (const float*)d_in[17];
    const float* b_hh0 = (const float*)d_in[18];
    const float* w_ih1 = (const float*)d_in[19];
    const float* w_hh1 = (const float*)d_in[20];
    const float* b_ih1 = (const float*)d_in[21];
    const float* b_hh1 = (const float*)d_in[22];
    const int* eA_src = (const int*)d_in[23];   // svc -> svc
    const int* eA_dst = (const int*)d_in[24];
    const int* eB_src = (const int*)d_in[25];   // pod -> node
    const int* eB_dst = (const int*)d_in[26];
    const int* eC_src = (const int*)d_in[27];   // node -> pod
    const int* eC_dst = (const int*)d_in[28];

    float* ws = (float*)d_ws;
    // layout (4B units)
    float* ocA = ws + 0;        // 2000
    float* icA = ws + 2000;     // 2000
    float* ocB = ws + 4000;     // 8000 (pod out-deg)
    float* icB = ws + 12000;    // 1000 (node in-deg)
    float* ocC = ws + 13000;    // 1000 (node out-deg)
    float* icC = ws + 14000;    // 8000 (pod in-deg)
    int* curA = (int*)(ws + 22000);  // 2000
    int* curB = (int*)(ws + 24000);  // 1000
    int* curC = (int*)(ws + 25000);  // 8000
    int* offA = (int*)(ws + 33000);  // 2001
    int* offB = (int*)(ws + 35001);  // 1001
    int* offC = (int*)(ws + 36002);  // 8001
    int* sA   = (int*)(ws + 44003);  // 30000
    int* sB   = (int*)(ws + 74003);  // 24000
    int* sC   = (int*)(ws + 98003);  // 24000
    float* xseq = ws + 122003;       // 11000*32
    float* X1   = ws + 474003;       // 11000*512
    float* h1   = ws + 6106003;      // 11000*128
    int* flags1  = (int*)(ws + 7514003);   // NCH
    int* flags2a = flags1 + NCH;           // NCH
    int* flags2b = flags2a + NCH;          // NCH
    float* X2   = X1;   // layer-2 proj overwrites X1 chunk-in-place (gated by flags1)

    // zero deg counts + cursors + pipeline flags
    hipMemsetAsync(d_ws, 0, 33000 * sizeof(float), stream);
    hipMemsetAsync(flags1, 0, 3 * NCH * sizeof(int), stream);

    k_count3<<<(ETOT + 255) / 256, 256, 0, stream>>>(
        eA_src, eA_dst, eB_src, eB_dst, eC_src, eC_dst,
        ocA, icA, ocB, icB, ocC, icC);

    k_scan<<<3, 256, 0, stream>>>(icA, NSVC, offA, icB, NNODE, offB, icC, NPOD, offC);

    k_scatter3<<<(ETOT + 255) / 256, 256, 0, stream>>>(
        eA_src, eA_dst, eB_src, eB_dst, eC_src, eC_dst,
        offA, curA, sA, offB, curB, sB, offC, curC, sC);

    // merged convs: A rows [0,2000), C rows [2000,10000), B rows [10000,11000)
    k_conv3<<<dim3(TT, YA16 + YC16 + YB16), 256, 0, stream>>>(
        feat_svc, feat_pod, feat_node,
        w_svc, b_svc, lw_svc, lb_svc,
        w_ni, b_ni, lw_pod, lb_pod,
        w_in, b_in, lw_node, lb_node,
        ocA, icA, offA, sA,
        ocC, icC, offC, sC,
        ocB, icB, offB, sB,
        xseq);

    // layer-1 input projection (parallel GEMM, permuted X layout)
    k_proj<<<(NTOT + 15) / 16, 256, 0, stream>>>(xseq, TT, w_ih0, b_ih0, b_hh0, X1, NTOT);

    // 4-block pipelined LSTM: L1 rec | proj(rows 0-255) | proj(rows 256-511) | L2 rec
    k_pipe<<<4, 256, 0, stream>>>(X1, w_hh0, h1, w_ih1, b_ih1, b_hh1,
                                  X2, w_hh1, (float*)d_out, flags1, flags2a, flags2b);
}

// Round 8
// 11692.509 us; speedup vs baseline: 1.4527x; 1.4527x over previous
//
#include <hip/hip_runtime.h>

#define NSVC 2000
#define NPOD 8000
#define NNODE 1000
#define NTOT 11000
#define TT 32
#define FF 64
#define HH 128
#define EA 30000
#define EB 24000
#define EC 24000
#define ETOT (EA + EB + EC)
#define CHK 64
#define NCH ((NTOT + CHK - 1) / CHK)   // 172 (all chunk lengths even)

// ---------------- agent-scope helpers (cross-XCD safe) ----------------
__device__ __forceinline__ float ld_agent(const float* p) {
    return __hip_atomic_load(p, __ATOMIC_RELAXED, __HIP_MEMORY_SCOPE_AGENT);
}
__device__ __forceinline__ void st_agent(float* p, float v) {
    __hip_atomic_store(p, v, __ATOMIC_RELAXED, __HIP_MEMORY_SCOPE_AGENT);
}
// barrier that does NOT drain vmcnt (keeps global loads/stores in flight)
__device__ __forceinline__ void bar_fast() {
    asm volatile("s_waitcnt lgkmcnt(0)" ::: "memory");
    __builtin_amdgcn_s_barrier();
}
// DPP quad_perm: xor1=0xB1 [1,0,3,2], xor2=0x4E [2,3,0,1], bcast q0..q3=0x00,0x55,0xAA,0xFF
template<int CTRL>
__device__ __forceinline__ float qperm(float x) {
    return __int_as_float(__builtin_amdgcn_mov_dpp(__float_as_int(x), CTRL, 0xF, 0xF, false));
}

// ---------------- merged degree counting ----------------
__global__ void k_count3(const int* __restrict__ sA, const int* __restrict__ dA,
                         const int* __restrict__ sB, const int* __restrict__ dB,
                         const int* __restrict__ sC, const int* __restrict__ dC,
                         float* ocA, float* icA, float* ocB, float* icB,
                         float* ocC, float* icC) {
    int e = blockIdx.x * 256 + threadIdx.x;
    if (e < EA) {
        atomicAdd(ocA + sA[e], 1.f); atomicAdd(icA + dA[e], 1.f);
    } else if (e < EA + EB) {
        int i = e - EA;
        atomicAdd(ocB + sB[i], 1.f); atomicAdd(icB + dB[i], 1.f);
    } else if (e < ETOT) {
        int i = e - EA - EB;
        atomicAdd(ocC + sC[i], 1.f); atomicAdd(icC + dC[i], 1.f);
    }
}

// ---------------- prefix scan (3 graphs, one block each) ----------------
__global__ void k_scan(const float* cA, int nA, int* oA,
                       const float* cB, int nB, int* oB,
                       const float* cC, int nC, int* oC) {
    const float* c; int n; int* o;
    if (blockIdx.x == 0)      { c = cA; n = nA; o = oA; }
    else if (blockIdx.x == 1) { c = cB; n = nB; o = oB; }
    else                      { c = cC; n = nC; o = oC; }
    __shared__ int s[256];
    __shared__ int carry;
    int tid = threadIdx.x;
    if (tid == 0) { carry = 0; o[0] = 0; }
    __syncthreads();
    for (int base = 0; base < n; base += 256) {
        int idx = base + tid;
        int v = (idx < n) ? (int)c[idx] : 0;
        s[tid] = v;
        __syncthreads();
        for (int d = 1; d < 256; d <<= 1) {
            int t = (tid >= d) ? s[tid - d] : 0;
            __syncthreads();
            s[tid] += t;
            __syncthreads();
        }
        if (idx < n) o[idx + 1] = carry + s[tid];
        __syncthreads();
        if (tid == 255) carry += s[255];
        __syncthreads();
    }
}

// ---------------- merged CSR scatter ----------------
__global__ void k_scatter3(const int* __restrict__ sA, const int* __restrict__ dA,
                           const int* __restrict__ sB, const int* __restrict__ dB,
                           const int* __restrict__ sC, const int* __restrict__ dC,
                           const int* offA, int* curA, int* csrA,
                           const int* offB, int* curB, int* csrB,
                           const int* offC, int* curC, int* csrC) {
    int e = blockIdx.x * 256 + threadIdx.x;
    if (e < EA) {
        int d = dA[e]; int p = atomicAdd(curA + d, 1); csrA[offA[d] + p] = sA[e];
    } else if (e < EA + EB) {
        int i = e - EA;
        int d = dB[i]; int p = atomicAdd(curB + d, 1); csrB[offB[d] + p] = sB[i];
    } else if (e < ETOT) {
        int i = e - EA - EB;
        int d = dC[i]; int p = atomicAdd(curC + d, 1); csrC[offC[d] + p] = sC[i];
    }
}

// ---------------- fused conv (3 graphs merged, 16 dst/block) ----------------
#define YA16 ((NSVC + 15) / 16)    // 125
#define YC16 ((NPOD + 15) / 16)    // 500
#define YB16 ((NNODE + 15) / 16)   // 63
__global__ __launch_bounds__(256) void k_conv3(
    const float* __restrict__ feat_svc, const float* __restrict__ feat_pod,
    const float* __restrict__ feat_node,
    const float* __restrict__ w_svc, const float* __restrict__ b_svc,
    const float* __restrict__ lw_svc, const float* __restrict__ lb_svc,
    const float* __restrict__ w_ni, const float* __restrict__ b_ni,
    const float* __restrict__ lw_pod, const float* __restrict__ lb_pod,
    const float* __restrict__ w_in, const float* __restrict__ b_in,
    const float* __restrict__ lw_node, const float* __restrict__ lb_node,
    const float* ocA, const float* icA, const int* offA, const int* csrA,
    const float* ocC, const float* icC, const int* offC, const int* csrC,
    const float* ocB, const float* icB, const int* offB, const int* csrB,
    float* __restrict__ xseq)
{
    __shared__ float wl[FF * HH];
    __shared__ float bl[HH], lwl[HH];
    __shared__ float accs[4][FF];
    const int t = blockIdx.x;
    const int tid = threadIdx.x;
    int yb = blockIdx.y;
    const float *x, *w, *b, *lw, *lb, *oc, *ic; const int *off, *csr;
    int Ndst, rowofs;
    if (yb < YA16) {
        x = feat_svc; w = w_svc; b = b_svc; lw = lw_svc; lb = lb_svc;
        oc = ocA; ic = icA; off = offA; csr = csrA; Ndst = NSVC; rowofs = 0;
    } else if (yb < YA16 + YC16) {
        yb -= YA16;
        x = feat_node; w = w_ni; b = b_ni; lw = lw_pod; lb = lb_pod;
        oc = ocC; ic = icC; off = offC; csr = csrC; Ndst = NPOD; rowofs = NSVC;
    } else {
        yb -= YA16 + YC16;
        x = feat_pod; w = w_in; b = b_in; lw = lw_node; lb = lb_node;
        oc = ocB; ic = icB; off = offB; csr = csrB; Ndst = NNODE; rowofs = NSVC + NPOD;
    }
    for (int i = tid; i < FF * HH; i += 256) wl[i] = w[t * FF * HH + i];
    if (tid < HH) { bl[tid] = b[t * HH + tid]; lwl[tid] = lw[t * HH + tid]; }
    const int wv = tid >> 6, lane = tid & 63;
    __syncthreads();
    for (int sub = 0; sub < 4; ++sub) {
        const int dstn = yb * 16 + sub * 4 + wv;
        if (dstn < Ndst) {
            float a = 0.f;
            const int e0 = off[dstn], e1 = off[dstn + 1];
            const float* xb = x + (size_t)t * FF + lane;
            float xsP = 0.f, ocP = 1.f;
            if (e0 < e1) {
                int s0 = csr[e0];
                xsP = xb[(size_t)s0 * (TT * FF)]; ocP = oc[s0];
            }
            for (int i = e0; i < e1; ++i) {
                float xs = xsP, od = ocP;
                if (i + 1 < e1) {
                    int s2 = csr[i + 1];
                    xsP = xb[(size_t)s2 * (TT * FF)]; ocP = oc[s2];
                }
                a = fmaf(xs, rsqrtf(fmaxf(od, 1.f)), a);
            }
            a *= rsqrtf(fmaxf(ic[dstn], 1.f));
            accs[wv][lane] = a;     // wave-local: write then read by same wave
            float h0 = bl[lane], h1v = bl[64 + lane];
            #pragma unroll
            for (int f = 0; f < FF; ++f) {
                float af = accs[wv][f];
                h0  = fmaf(af, wl[f * HH + lane], h0);
                h1v = fmaf(af, wl[f * HH + 64 + lane], h1v);
            }
            h0  = (h0  >= 0.f) ? h0  : 0.01f * h0;
            h1v = (h1v >= 0.f) ? h1v : 0.01f * h1v;
            float p = h0 * lwl[lane] + h1v * lwl[64 + lane];
            #pragma unroll
            for (int o2 = 32; o2 >= 1; o2 >>= 1) p += __shfl_down(p, o2);
            if (lane == 0) xseq[(size_t)(rowofs + dstn) * TT + t] = p + lb[t];
        }
    }
}

// X layout: gate-major row r = g*128+j stored at column (j<<2)|g, so rec lane
// tid = 4j+p reads X[n*512 + tid] coalesced (lane p owns gate p's X value).
__device__ __forceinline__ int xcol(int r) { return ((r & 127) << 2) | (r >> 7); }

// ---------------- input projection (layer 1): X = xin @ wih^T + (bih + bhh) --------
__global__ __launch_bounds__(256) void k_proj(
    const float* __restrict__ xin, int K,      // [N, K]
    const float* __restrict__ wih,             // [512, K]
    const float* __restrict__ bih, const float* __restrict__ bhh,
    float* __restrict__ Xout, int N)           // [N, 512] permuted cols
{
    __shared__ float xt[16 * 128];
    int n0 = blockIdx.x * 16, tid = threadIdx.x;
    for (int i = tid; i < 16 * K; i += 256) {
        int nn = i / K, kk = i - nn * K;
        int n = n0 + nn;
        xt[i] = (n < N) ? xin[(size_t)n * K + kk] : 0.f;
    }
    __syncthreads();
    float acc0[16], acc1[16];
    #pragma unroll
    for (int i = 0; i < 16; ++i) { acc0[i] = 0.f; acc1[i] = 0.f; }
    int r0 = tid, r1 = tid + 256;
    for (int k = 0; k < K; ++k) {
        float w0 = wih[(size_t)r0 * K + k];
        float w1 = wih[(size_t)r1 * K + k];
        #pragma unroll
        for (int i = 0; i < 16; ++i) {
            float xv = xt[i * K + k];
            acc0[i] = fmaf(xv, w0, acc0[i]);
            acc1[i] = fmaf(xv, w1, acc1[i]);
        }
    }
    float b0 = bih[r0] + bhh[r0], b1 = bih[r1] + bhh[r1];
    int c0 = xcol(r0), c1 = xcol(r1);
    for (int i = 0; i < 16; ++i) {
        int n = n0 + i;
        if (n < N) {
            Xout[(size_t)n * 512 + c0] = acc0[i] + b0;
            Xout[(size_t)n * 512 + c1] = acc1[i] + b1;
        }
    }
}

// ---------------- sequential LSTM recurrence (one block = one CU, 512 thr) --------
// thread = (j,p): unit j = tid>>2, k-chunk p = tid&3 (G=4 traffic-optimal mapping).
// w[4][32] = 128 floats/thread MUST be VGPR-resident: amdgpu_waves_per_eu(2,2)
// on k_pipe gives each of the 2 waves/SIMD a 256-VGPR budget. All bools are
// template-constant so the allocator sees straight-line loop code.
template<bool AGX, bool AGH, bool WAIT, bool SIG>
__device__ __forceinline__ void lstm_rec(
    const float* __restrict__ X, const float* __restrict__ Whh,
    float* __restrict__ Hout, int* wflag, int* sflag)
{
    __shared__ __align__(16) float hb0s[4 * 36], hb1s[4 * 36];  // stride 36: conflict-free
    const int tid = threadIdx.x;
    const int j = tid >> 2, p = tid & 3;
    // w[g] = Whh row (g*128+j), k-slice [32p, 32p+32) — 8 float4 per gate
    float4 w0[8], w1[8], w2[8], w3[8];
    {
        const float* bj = Whh + (size_t)j * HH + p * 32;
        const float4* r0 = reinterpret_cast<const float4*>(bj);
        const float4* r1 = reinterpret_cast<const float4*>(bj + 128 * HH);
        const float4* r2 = reinterpret_cast<const float4*>(bj + 256 * HH);
        const float4* r3 = reinterpret_cast<const float4*>(bj + 384 * HH);
        #pragma unroll
        for (int q = 0; q < 8; ++q) { w0[q]=r0[q]; w1[q]=r1[q]; w2[q]=r2[q]; w3[q]=r3[q]; }
    }
    if (tid < HH) hb0s[(tid >> 5) * 36 + (tid & 31)] = 0.f;
    // sigmoid (p=0,1,3): a = 1/(1+e^-s); tanh (p=2): a = 1 - 2/(1+e^2s)
    const float k1 = (p == 2) ? -2.f : 1.f;
    const float k2 = (p == 2) ? 2.f : -1.f;
    const float k3 = (p == 2) ? 1.f : 0.f;
    const bool pa = (p & 1) != 0, pb = (p & 2) != 0;
    const int hst = (j >> 5) * 36 + (j & 31);
    float c = 0.f;   // identical across each 4-lane quad
    __syncthreads();

#define REC_STEP(HSRC, HDST, XC, HOPTR)                                          \
    {                                                                            \
        const float4* hr = reinterpret_cast<const float4*>((HSRC) + p * 36);     \
        float s0 = 0.f, s1 = 0.f, s2 = 0.f, s3 = 0.f;                            \
        _Pragma("unroll")                                                        \
        for (int q = 0; q < 8; ++q) {                                            \
            float4 h4 = hr[q];                                                   \
            s0 = fmaf(w0[q].x, h4.x, s0); s0 = fmaf(w0[q].y, h4.y, s0);          \
            s0 = fmaf(w0[q].z, h4.z, s0); s0 = fmaf(w0[q].w, h4.w, s0);          \
            s1 = fmaf(w1[q].x, h4.x, s1); s1 = fmaf(w1[q].y, h4.y, s1);          \
            s1 = fmaf(w1[q].z, h4.z, s1); s1 = fmaf(w1[q].w, h4.w, s1);          \
            s2 = fmaf(w2[q].x, h4.x, s2); s2 = fmaf(w2[q].y, h4.y, s2);          \
            s2 = fmaf(w2[q].z, h4.z, s2); s2 = fmaf(w2[q].w, h4.w, s2);          \
            s3 = fmaf(w3[q].x, h4.x, s3); s3 = fmaf(w3[q].y, h4.y, s3);          \
            s3 = fmaf(w3[q].z, h4.z, s3); s3 = fmaf(w3[q].w, h4.w, s3);          \
        }                                                                        \
        float zA = pa ? s0 : s1;                                                 \
        float u  = (pa ? s1 : s0) + qperm<0xB1>(zA);                             \
        float zB = pa ? s2 : s3;                                                 \
        float v  = (pa ? s3 : s2) + qperm<0xB1>(zB);                             \
        float zC = pb ? u : v;                                                   \
        float sf = ((pb ? v : u) + qperm<0x4E>(zC)) + (XC);                      \
        float ev = __expf(k2 * sf);                                              \
        float a  = fmaf(k1, __builtin_amdgcn_rcpf(1.f + ev), k3);                \
        float ai = qperm<0x00>(a);                                               \
        float af = qperm<0x55>(a);                                               \
        float ag = qperm<0xAA>(a);                                               \
        float ao = qperm<0xFF>(a);                                               \
        c = fmaf(af, c, ai * ag);                                                \
        float e2 = __expf(2.f * c);                                              \
        float th = fmaf(-2.f, __builtin_amdgcn_rcpf(1.f + e2), 1.f);             \
        float hnew = ao * th;                                                    \
        if (p == 0) {                                                            \
            (HDST)[hst] = hnew;                                                  \
            if (AGH) st_agent((HOPTR), hnew); else *(HOPTR) = hnew;              \
        }                                                                        \
        bar_fast();                                                              \
    }

    for (int ch = 0; ch < NCH; ++ch) {
        const int n0 = ch * CHK;
        const int n1 = (n0 + CHK < NTOT) ? (n0 + CHK) : NTOT;   // even count
        if (WAIT) {
            if (tid == 0) {
                while (__hip_atomic_load(wflag + ch, __ATOMIC_RELAXED, __HIP_MEMORY_SCOPE_AGENT) == 0)
                    __builtin_amdgcn_s_sleep(1);
            }
            __syncthreads();
            __threadfence();   // acquire
        }
        const float* xb = X + (size_t)n0 * 512 + tid;    // coalesced (xcol layout)
        float* hop = Hout + (size_t)n0 * HH + j;
        float xc0 = AGX ? ld_agent(xb) : xb[0];
        float xc1 = AGX ? ld_agent(xb + 512) : xb[512];
        for (int n = n0; n < n1; n += 2) {
            float xp2 = 0.f, xp3 = 0.f;
            if (n + 2 < n1) {
                xp2 = AGX ? ld_agent(xb + 1024) : xb[1024];
                xp3 = AGX ? ld_agent(xb + 1536) : xb[1536];
            }
            REC_STEP(hb0s, hb1s, xc0, hop)
            REC_STEP(hb1s, hb0s, xc1, hop + HH)
            xc0 = xp2; xc1 = xp3;
            xb += 1024; hop += 2 * HH;
        }
        if (SIG) {
            __syncthreads();   // full drain: h stores visible before flag
            if (tid == 0)
                __hip_atomic_store(sflag + ch, 1, __ATOMIC_RELEASE, __HIP_MEMORY_SCOPE_AGENT);
        }
    }
#undef REC_STEP
}

// ---------------- layer-2 input projection worker (pipelined, 512 thr) ----------
__device__ __forceinline__ void proj_work(
    const float* __restrict__ h1, const float* __restrict__ Wih,
    const float* __restrict__ bih, const float* __restrict__ bhh,
    float* __restrict__ X2, int* wflag, int* sflag)
{
    __shared__ float hl[CHK * HH];     // 32 KB
    const int tid = threadIdx.x;       // row r of W_ih1 (gate-major)
    const float bsum = bih[tid] + bhh[tid];
    const int col = xcol(tid);
    const float4* wr = reinterpret_cast<const float4*>(Wih + (size_t)tid * HH);
    for (int ch = 0; ch < NCH; ++ch) {
        const int n0 = ch * CHK;
        const int cnt = (n0 + CHK < NTOT) ? CHK : (NTOT - n0);
        if (tid == 0) {
            while (__hip_atomic_load(wflag + ch, __ATOMIC_RELAXED, __HIP_MEMORY_SCOPE_AGENT) == 0)
                __builtin_amdgcn_s_sleep(1);
        }
        __syncthreads();
        __threadfence();
        for (int i = tid; i < cnt * HH; i += 512)
            hl[i] = ld_agent(h1 + (size_t)n0 * HH + i);
        __syncthreads();
        for (int t0 = 0; t0 < cnt; t0 += 16) {
            float acc[16];
            #pragma unroll
            for (int i = 0; i < 16; ++i) acc[i] = bsum;
            for (int k4 = 0; k4 < HH / 4; ++k4) {
                float4 wv = wr[k4];
                #pragma unroll
                for (int i = 0; i < 16; ++i) {
                    const float* hh = &hl[(t0 + i) * HH + 4 * k4];
                    acc[i] += wv.x*hh[0] + wv.y*hh[1] + wv.z*hh[2] + wv.w*hh[3];
                }
            }
            int tl = cnt - t0; if (tl > 16) tl = 16;
            for (int i = 0; i < tl; ++i)
                st_agent(X2 + (size_t)(n0 + t0 + i) * 512 + col, acc[i]);
        }
        __syncthreads();   // drain stores
        if (tid == 0)
            __hip_atomic_store(sflag + ch, 1, __ATOMIC_RELEASE, __HIP_MEMORY_SCOPE_AGENT);
    }
}

// ---------------- 3-stage pipeline: L1 rec -> proj -> L2 rec ----------------
// waves_per_eu(2,2): exactly 2 waves/SIMD -> each wave may use the full half-file
// (256 VGPRs) — the weights stay resident (prediction: VGPR_Count ~200+).
__global__ __launch_bounds__(512)
__attribute__((amdgpu_waves_per_eu(2, 2)))
void k_pipe(
    const float* __restrict__ X1, const float* __restrict__ w_hh0, float* __restrict__ h1,
    const float* __restrict__ w_ih1, const float* __restrict__ b_ih1, const float* __restrict__ b_hh1,
    float* __restrict__ X2, const float* __restrict__ w_hh1, float* __restrict__ out,
    int* flags1, int* flags2)
{
    if (blockIdx.x == 0)
        lstm_rec<false, true, false, true>(X1, w_hh0, h1, nullptr, flags1);
    else if (blockIdx.x == 1)
        proj_work(h1, w_ih1, b_ih1, b_hh1, X2, flags1, flags2);
    else
        lstm_rec<true, false, true, false>(X2, w_hh1, out, flags2, nullptr);
}

extern "C" void kernel_launch(void* const* d_in, const int* in_sizes, int n_in,
                              void* d_out, int out_size, void* d_ws, size_t ws_size,
                              hipStream_t stream) {
    const float* feat_svc = (const float*)d_in[0];
    const float* feat_pod = (const float*)d_in[1];
    const float* feat_node= (const float*)d_in[2];
    const float* w_svc = (const float*)d_in[3];
    const float* b_svc = (const float*)d_in[4];
    const float* w_in  = (const float*)d_in[5];
    const float* b_in  = (const float*)d_in[6];
    const float* w_ni  = (const float*)d_in[7];
    const float* b_ni  = (const float*)d_in[8];
    const float* lw_svc = (const float*)d_in[9];
    const float* lb_svc = (const float*)d_in[10];
    const float* lw_pod = (const float*)d_in[11];
    const float* lb_pod = (const float*)d_in[12];
    const float* lw_node= (const float*)d_in[13];
    const float* lb_node= (const float*)d_in[14];
    const float* w_ih0 = (const float*)d_in[15];
    const float* w_hh0 = (const float*)d_in[16];
    const float* b_ih0 = (const float*)d_in[17];
    const float* b_hh0 = (const float*)d_in[18];
    const float* w_ih1 = (const float*)d_in[19];
    const float* w_hh1 = (const float*)d_in[20];
    const float* b_ih1 = (const float*)d_in[21];
    const float* b_hh1 = (const float*)d_in[22];
    const int* eA_src = (const int*)d_in[23];   // svc -> svc
    const int* eA_dst = (const int*)d_in[24];
    const int* eB_src = (const int*)d_in[25];   // pod -> node
    const int* eB_dst = (const int*)d_in[26];
    const int* eC_src = (const int*)d_in[27];   // node -> pod
    const int* eC_dst = (const int*)d_in[28];

    float* ws = (float*)d_ws;
    // layout (4B units)
    float* ocA = ws + 0;        // 2000
    float* icA = ws + 2000;     // 2000
    float* ocB = ws + 4000;     // 8000 (pod out-deg)
    float* icB = ws + 12000;    // 1000 (node in-deg)
    float* ocC = ws + 13000;    // 1000 (node out-deg)
    float* icC = ws + 14000;    // 8000 (pod in-deg)
    int* curA = (int*)(ws + 22000);  // 2000
    int* curB = (int*)(ws + 24000);  // 1000
    int* curC = (int*)(ws + 25000);  // 8000
    int* offA = (int*)(ws + 33000);  // 2001
    int* offB = (int*)(ws + 35001);  // 1001
    int* offC = (int*)(ws + 36002);  // 8001
    int* sA   = (int*)(ws + 44003);  // 30000
    int* sB   = (int*)(ws + 74003);  // 24000
    int* sC   = (int*)(ws + 98003);  // 24000
    float* xseq = ws + 122003;       // 11000*32
    float* X1   = ws + 474003;       // 11000*512
    float* h1   = ws + 6106003;      // 11000*128
    int* flags1 = (int*)(ws + 7514003);   // NCH
    int* flags2 = flags1 + NCH;           // NCH
    float* X2   = X1;   // layer-2 proj overwrites X1 chunk-in-place (gated by flags1)

    // zero deg counts + cursors + pipeline flags
    hipMemsetAsync(d_ws, 0, 33000 * sizeof(float), stream);
    hipMemsetAsync(flags1, 0, 2 * NCH * sizeof(int), stream);

    k_count3<<<(ETOT + 255) / 256, 256, 0, stream>>>(
        eA_src, eA_dst, eB_src, eB_dst, eC_src, eC_dst,
        ocA, icA, ocB, icB, ocC, icC);

    k_scan<<<3, 256, 0, stream>>>(icA, NSVC, offA, icB, NNODE, offB, icC, NPOD, offC);

    k_scatter3<<<(ETOT + 255) / 256, 256, 0, stream>>>(
        eA_src, eA_dst, eB_src, eB_dst, eC_src, eC_dst,
        offA, curA, sA, offB, curB, sB, offC, curC, sC);

    // merged convs: A rows [0,2000), C rows [2000,10000), B rows [10000,11000)
    k_conv3<<<dim3(TT, YA16 + YC16 + YB16), 256, 0, stream>>>(
        feat_svc, feat_pod, feat_node,
        w_svc, b_svc, lw_svc, lb_svc,
        w_ni, b_ni, lw_pod, lb_pod,
        w_in, b_in, lw_node, lb_node,
        ocA, icA, offA, sA,
        ocC, icC, offC, sC,
        ocB, icB, offB, sB,
        xseq);

    // layer-1 input projection (parallel GEMM, permuted X layout)
    k_proj<<<(NTOT + 15) / 16, 256, 0, stream>>>(xseq, TT, w_ih0, b_ih0, b_hh0, X1, NTOT);

    // 3-stage pipelined LSTM: L1 recurrence -> L2 proj -> L2 recurrence
    k_pipe<<<3, 512, 0, stream>>>(X1, w_hh0, h1, w_ih1, b_ih1, b_hh1,
                                  X2, w_hh1, (float*)d_out, flags1, flags2);
}

// Round 9
// 11041.335 us; speedup vs baseline: 1.5384x; 1.0590x over previous
//
#include <hip/hip_runtime.h>

#define NSVC 2000
#define NPOD 8000
#define NNODE 1000
#define NTOT 11000
#define TT 32
#define FF 64
#define HH 128
#define EA 30000
#define EB 24000
#define EC 24000
#define ETOT (EA + EB + EC)
#define CHK 64
#define NCH ((NTOT + CHK - 1) / CHK)   // 172 (all chunk lengths even)

// ---------------- agent-scope helpers (cross-XCD safe) ----------------
__device__ __forceinline__ float ld_agent(const float* p) {
    return __hip_atomic_load(p, __ATOMIC_RELAXED, __HIP_MEMORY_SCOPE_AGENT);
}
__device__ __forceinline__ void st_agent(float* p, float v) {
    __hip_atomic_store(p, v, __ATOMIC_RELAXED, __HIP_MEMORY_SCOPE_AGENT);
}
// barrier that does NOT drain vmcnt (keeps global loads/stores in flight)
__device__ __forceinline__ void bar_fast() {
    asm volatile("s_waitcnt lgkmcnt(0)" ::: "memory");
    __builtin_amdgcn_s_barrier();
}
// DPP quad_perm: xor1=0xB1 [1,0,3,2], xor2=0x4E [2,3,0,1], bcast q0..q3=0x00,0x55,0xAA,0xFF
template<int CTRL>
__device__ __forceinline__ float qperm(float x) {
    return __int_as_float(__builtin_amdgcn_mov_dpp(__float_as_int(x), CTRL, 0xF, 0xF, false));
}
// lane ^ 4 cross-lane (BitMode swizzle: and=0x1F, or=0, xor=4)
__device__ __forceinline__ float swz_xor4(float x) {
    return __int_as_float(__builtin_amdgcn_ds_swizzle(__float_as_int(x), 0x101F));
}

// ---------------- merged degree counting ----------------
__global__ void k_count3(const int* __restrict__ sA, const int* __restrict__ dA,
                         const int* __restrict__ sB, const int* __restrict__ dB,
                         const int* __restrict__ sC, const int* __restrict__ dC,
                         float* ocA, float* icA, float* ocB, float* icB,
                         float* ocC, float* icC) {
    int e = blockIdx.x * 256 + threadIdx.x;
    if (e < EA) {
        atomicAdd(ocA + sA[e], 1.f); atomicAdd(icA + dA[e], 1.f);
    } else if (e < EA + EB) {
        int i = e - EA;
        atomicAdd(ocB + sB[i], 1.f); atomicAdd(icB + dB[i], 1.f);
    } else if (e < ETOT) {
        int i = e - EA - EB;
        atomicAdd(ocC + sC[i], 1.f); atomicAdd(icC + dC[i], 1.f);
    }
}

// ---------------- prefix scan (3 graphs, one block each) ----------------
__global__ void k_scan(const float* cA, int nA, int* oA,
                       const float* cB, int nB, int* oB,
                       const float* cC, int nC, int* oC) {
    const float* c; int n; int* o;
    if (blockIdx.x == 0)      { c = cA; n = nA; o = oA; }
    else if (blockIdx.x == 1) { c = cB; n = nB; o = oB; }
    else                      { c = cC; n = nC; o = oC; }
    __shared__ int s[256];
    __shared__ int carry;
    int tid = threadIdx.x;
    if (tid == 0) { carry = 0; o[0] = 0; }
    __syncthreads();
    for (int base = 0; base < n; base += 256) {
        int idx = base + tid;
        int v = (idx < n) ? (int)c[idx] : 0;
        s[tid] = v;
        __syncthreads();
        for (int d = 1; d < 256; d <<= 1) {
            int t = (tid >= d) ? s[tid - d] : 0;
            __syncthreads();
            s[tid] += t;
            __syncthreads();
        }
        if (idx < n) o[idx + 1] = carry + s[tid];
        __syncthreads();
        if (tid == 255) carry += s[255];
        __syncthreads();
    }
}

// ---------------- merged CSR scatter ----------------
__global__ void k_scatter3(const int* __restrict__ sA, const int* __restrict__ dA,
                           const int* __restrict__ sB, const int* __restrict__ dB,
                           const int* __restrict__ sC, const int* __restrict__ dC,
                           const int* offA, int* curA, int* csrA,
                           const int* offB, int* curB, int* csrB,
                           const int* offC, int* curC, int* csrC) {
    int e = blockIdx.x * 256 + threadIdx.x;
    if (e < EA) {
        int d = dA[e]; int p = atomicAdd(curA + d, 1); csrA[offA[d] + p] = sA[e];
    } else if (e < EA + EB) {
        int i = e - EA;
        int d = dB[i]; int p = atomicAdd(curB + d, 1); csrB[offB[d] + p] = sB[i];
    } else if (e < ETOT) {
        int i = e - EA - EB;
        int d = dC[i]; int p = atomicAdd(curC + d, 1); csrC[offC[d] + p] = sC[i];
    }
}

// ---------------- fused conv (3 graphs merged, 16 dst/block) ----------------
#define YA16 ((NSVC + 15) / 16)    // 125
#define YC16 ((NPOD + 15) / 16)    // 500
#define YB16 ((NNODE + 15) / 16)   // 63
__global__ __launch_bounds__(256) void k_conv3(
    const float* __restrict__ feat_svc, const float* __restrict__ feat_pod,
    const float* __restrict__ feat_node,
    const float* __restrict__ w_svc, const float* __restrict__ b_svc,
    const float* __restrict__ lw_svc, const float* __restrict__ lb_svc,
    const float* __restrict__ w_ni, const float* __restrict__ b_ni,
    const float* __restrict__ lw_pod, const float* __restrict__ lb_pod,
    const float* __restrict__ w_in, const float* __restrict__ b_in,
    const float* __restrict__ lw_node, const float* __restrict__ lb_node,
    const float* ocA, const float* icA, const int* offA, const int* csrA,
    const float* ocC, const float* icC, const int* offC, const int* csrC,
    const float* ocB, const float* icB, const int* offB, const int* csrB,
    float* __restrict__ xseq)
{
    __shared__ float wl[FF * HH];
    __shared__ float bl[HH], lwl[HH];
    __shared__ float accs[4][FF];
    const int t = blockIdx.x;
    const int tid = threadIdx.x;
    int yb = blockIdx.y;
    const float *x, *w, *b, *lw, *lb, *oc, *ic; const int *off, *csr;
    int Ndst, rowofs;
    if (yb < YA16) {
        x = feat_svc; w = w_svc; b = b_svc; lw = lw_svc; lb = lb_svc;
        oc = ocA; ic = icA; off = offA; csr = csrA; Ndst = NSVC; rowofs = 0;
    } else if (yb < YA16 + YC16) {
        yb -= YA16;
        x = feat_node; w = w_ni; b = b_ni; lw = lw_pod; lb = lb_pod;
        oc = ocC; ic = icC; off = offC; csr = csrC; Ndst = NPOD; rowofs = NSVC;
    } else {
        yb -= YA16 + YC16;
        x = feat_pod; w = w_in; b = b_in; lw = lw_node; lb = lb_node;
        oc = ocB; ic = icB; off = offB; csr = csrB; Ndst = NNODE; rowofs = NSVC + NPOD;
    }
    for (int i = tid; i < FF * HH; i += 256) wl[i] = w[t * FF * HH + i];
    if (tid < HH) { bl[tid] = b[t * HH + tid]; lwl[tid] = lw[t * HH + tid]; }
    const int wv = tid >> 6, lane = tid & 63;
    __syncthreads();
    for (int sub = 0; sub < 4; ++sub) {
        const int dstn = yb * 16 + sub * 4 + wv;
        if (dstn < Ndst) {
            float a = 0.f;
            const int e0 = off[dstn], e1 = off[dstn + 1];
            const float* xb = x + (size_t)t * FF + lane;
            float xsP = 0.f, ocP = 1.f;
            if (e0 < e1) {
                int s0 = csr[e0];
                xsP = xb[(size_t)s0 * (TT * FF)]; ocP = oc[s0];
            }
            for (int i = e0; i < e1; ++i) {
                float xs = xsP, od = ocP;
                if (i + 1 < e1) {
                    int s2 = csr[i + 1];
                    xsP = xb[(size_t)s2 * (TT * FF)]; ocP = oc[s2];
                }
                a = fmaf(xs, rsqrtf(fmaxf(od, 1.f)), a);
            }
            a *= rsqrtf(fmaxf(ic[dstn], 1.f));
            accs[wv][lane] = a;     // wave-local: write then read by same wave
            float h0 = bl[lane], h1v = bl[64 + lane];
            #pragma unroll
            for (int f = 0; f < FF; ++f) {
                float af = accs[wv][f];
                h0  = fmaf(af, wl[f * HH + lane], h0);
                h1v = fmaf(af, wl[f * HH + 64 + lane], h1v);
            }
            h0  = (h0  >= 0.f) ? h0  : 0.01f * h0;
            h1v = (h1v >= 0.f) ? h1v : 0.01f * h1v;
            float p = h0 * lwl[lane] + h1v * lwl[64 + lane];
            #pragma unroll
            for (int o2 = 32; o2 >= 1; o2 >>= 1) p += __shfl_down(p, o2);
            if (lane == 0) xseq[(size_t)(rowofs + dstn) * TT + t] = p + lb[t];
        }
    }
}

// X layout: gate-major row r = g*128+j stored at column (j<<2)|g.
__device__ __forceinline__ int xcol(int r) { return ((r & 127) << 2) | (r >> 7); }

// ---------------- input projection (layer 1): X = xin @ wih^T + (bih + bhh) --------
__global__ __launch_bounds__(256) void k_proj(
    const float* __restrict__ xin, int K,      // [N, K]
    const float* __restrict__ wih,             // [512, K]
    const float* __restrict__ bih, const float* __restrict__ bhh,
    float* __restrict__ Xout, int N)           // [N, 512] permuted cols
{
    __shared__ float xt[16 * 128];
    int n0 = blockIdx.x * 16, tid = threadIdx.x;
    for (int i = tid; i < 16 * K; i += 256) {
        int nn = i / K, kk = i - nn * K;
        int n = n0 + nn;
        xt[i] = (n < N) ? xin[(size_t)n * K + kk] : 0.f;
    }
    __syncthreads();
    float acc0[16], acc1[16];
    #pragma unroll
    for (int i = 0; i < 16; ++i) { acc0[i] = 0.f; acc1[i] = 0.f; }
    int r0 = tid, r1 = tid + 256;
    for (int k = 0; k < K; ++k) {
        float w0 = wih[(size_t)r0 * K + k];
        float w1 = wih[(size_t)r1 * K + k];
        #pragma unroll
        for (int i = 0; i < 16; ++i) {
            float xv = xt[i * K + k];
            acc0[i] = fmaf(xv, w0, acc0[i]);
            acc1[i] = fmaf(xv, w1, acc1[i]);
        }
    }
    float b0 = bih[r0] + bhh[r0], b1 = bih[r1] + bhh[r1];
    int c0 = xcol(r0), c1 = xcol(r1);
    for (int i = 0; i < 16; ++i) {
        int n = n0 + i;
        if (n < N) {
            Xout[(size_t)n * 512 + c0] = acc0[i] + b0;
            Xout[(size_t)n * 512 + c1] = acc1[i] + b1;
        }
    }
}

// ---------------- sequential LSTM recurrence (1024 threads = 16 waves) ------------
// thread = (j,p): unit j = tid>>3, k-slice p = tid&7 (16 k each). Weights:
// 64 floats/thread as 16 NAMED float4 SSA values (nothing to alloca; need ~100
// VGPR < forced 128 cap at 16 waves -> resident). Reduction over 8 lanes:
// 2 DPP quad rounds + 1 ds_swizzle xor4; quad broadcasts; redundant c in 8 lanes.
// h LDS in 8 groups of 16 floats, stride 20 -> the 8 distinct b128 read
// addresses hit disjoint bank quartets (conflict-free).
template<bool AGX, bool AGH, bool WAIT, bool SIG>
__device__ __forceinline__ void lstm_rec(
    const float* __restrict__ X, const float* __restrict__ Whh,
    float* __restrict__ Hout, int* wflag, int* sflag)
{
    __shared__ __align__(16) float hb0s[8 * 20], hb1s[8 * 20];
    const int tid = threadIdx.x;           // 0..1023
    const int j = tid >> 3, p = tid & 7;
    const int g4 = p & 3;
    // weights: gate g row (g*128+j), k-slice [16p, 16p+16) -> 4 float4 per gate
    const float* bj = Whh + (size_t)j * HH + p * 16;
    const float4* r0 = reinterpret_cast<const float4*>(bj);
    const float4* r1 = reinterpret_cast<const float4*>(bj + 128 * HH);
    const float4* r2 = reinterpret_cast<const float4*>(bj + 256 * HH);
    const float4* r3 = reinterpret_cast<const float4*>(bj + 384 * HH);
    float4 w00 = r0[0], w01 = r0[1], w02 = r0[2], w03 = r0[3];
    float4 w10 = r1[0], w11 = r1[1], w12 = r1[2], w13 = r1[3];
    float4 w20 = r2[0], w21 = r2[1], w22 = r2[2], w23 = r2[3];
    float4 w30 = r3[0], w31 = r3[1], w32 = r3[2], w33 = r3[3];
    if (tid < 160) hb0s[tid] = 0.f;
    // sigmoid (g4=0,1,3): a = 1/(1+e^-s); tanh (g4=2): a = 1 - 2/(1+e^2s)
    const float k1 = (g4 == 2) ? -2.f : 1.f;
    const float k2 = (g4 == 2) ? 2.f : -1.f;
    const float k3 = (g4 == 2) ? 1.f : 0.f;
    const bool pa = (p & 1) != 0, pb = (p & 2) != 0;
    const int hwr = ((j >> 4) * 20) + (j & 15);   // write slot for unit j
    const int hrd = p * 20;                       // read base for slice p
    const int xoff = (j << 2) | g4;               // X column for (unit j, gate g4)
    float c = 0.f;   // identical across each 8-lane group
    __syncthreads();

#define REC_STEP(HSRC, HDST, XC, HOPTR)                                          \
    {                                                                            \
        const float4* hr = reinterpret_cast<const float4*>((HSRC) + hrd);        \
        float4 hA = hr[0], hB = hr[1], hC = hr[2], hD = hr[3];                   \
        float s0 = w00.x * hA.x;                                                 \
        s0 = fmaf(w00.y, hA.y, s0); s0 = fmaf(w00.z, hA.z, s0);                  \
        s0 = fmaf(w00.w, hA.w, s0); s0 = fmaf(w01.x, hB.x, s0);                  \
        s0 = fmaf(w01.y, hB.y, s0); s0 = fmaf(w01.z, hB.z, s0);                  \
        s0 = fmaf(w01.w, hB.w, s0); s0 = fmaf(w02.x, hC.x, s0);                  \
        s0 = fmaf(w02.y, hC.y, s0); s0 = fmaf(w02.z, hC.z, s0);                  \
        s0 = fmaf(w02.w, hC.w, s0); s0 = fmaf(w03.x, hD.x, s0);                  \
        s0 = fmaf(w03.y, hD.y, s0); s0 = fmaf(w03.z, hD.z, s0);                  \
        s0 = fmaf(w03.w, hD.w, s0);                                              \
        float s1 = w10.x * hA.x;                                                 \
        s1 = fmaf(w10.y, hA.y, s1); s1 = fmaf(w10.z, hA.z, s1);                  \
        s1 = fmaf(w10.w, hA.w, s1); s1 = fmaf(w11.x, hB.x, s1);                  \
        s1 = fmaf(w11.y, hB.y, s1); s1 = fmaf(w11.z, hB.z, s1);                  \
        s1 = fmaf(w11.w, hB.w, s1); s1 = fmaf(w12.x, hC.x, s1);                  \
        s1 = fmaf(w12.y, hC.y, s1); s1 = fmaf(w12.z, hC.z, s1);                  \
        s1 = fmaf(w12.w, hC.w, s1); s1 = fmaf(w13.x, hD.x, s1);                  \
        s1 = fmaf(w13.y, hD.y, s1); s1 = fmaf(w13.z, hD.z, s1);                  \
        s1 = fmaf(w13.w, hD.w, s1);                                              \
        float s2 = w20.x * hA.x;                                                 \
        s2 = fmaf(w20.y, hA.y, s2); s2 = fmaf(w20.z, hA.z, s2);                  \
        s2 = fmaf(w20.w, hA.w, s2); s2 = fmaf(w21.x, hB.x, s2);                  \
        s2 = fmaf(w21.y, hB.y, s2); s2 = fmaf(w21.z, hB.z, s2);                  \
        s2 = fmaf(w21.w, hB.w, s2); s2 = fmaf(w22.x, hC.x, s2);                  \
        s2 = fmaf(w22.y, hC.y, s2); s2 = fmaf(w22.z, hC.z, s2);                  \
        s2 = fmaf(w22.w, hC.w, s2); s2 = fmaf(w23.x, hD.x, s2);                  \
        s2 = fmaf(w23.y, hD.y, s2); s2 = fmaf(w23.z, hD.z, s2);                  \
        s2 = fmaf(w23.w, hD.w, s2);                                              \
        float s3 = w30.x * hA.x;                                                 \
        s3 = fmaf(w30.y, hA.y, s3); s3 = fmaf(w30.z, hA.z, s3);                  \
        s3 = fmaf(w30.w, hA.w, s3); s3 = fmaf(w31.x, hB.x, s3);                  \
        s3 = fmaf(w31.y, hB.y, s3); s3 = fmaf(w31.z, hB.z, s3);                  \
        s3 = fmaf(w31.w, hB.w, s3); s3 = fmaf(w32.x, hC.x, s3);                  \
        s3 = fmaf(w32.y, hC.y, s3); s3 = fmaf(w32.z, hC.z, s3);                  \
        s3 = fmaf(w32.w, hC.w, s3); s3 = fmaf(w33.x, hD.x, s3);                  \
        s3 = fmaf(w33.y, hD.y, s3); s3 = fmaf(w33.z, hD.z, s3);                  \
        s3 = fmaf(w33.w, hD.w, s3);                                              \
        /* quad reduce-scatter: lane ends with gate g4 over its quad's 64 k */   \
        float zA = pa ? s0 : s1;                                                 \
        float u  = (pa ? s1 : s0) + qperm<0xB1>(zA);                             \
        float zB = pa ? s2 : s3;                                                 \
        float v  = (pa ? s3 : s2) + qperm<0xB1>(zB);                             \
        float zC = pb ? u : v;                                                   \
        float sf = (pb ? v : u) + qperm<0x4E>(zC);                               \
        /* xor4: sum the two 64-k halves (lanes p and p^4 hold same gate) */     \
        sf += swz_xor4(sf);                                                      \
        sf += (XC);                                                              \
        float ev = __expf(k2 * sf);                                              \
        float a  = fmaf(k1, __builtin_amdgcn_rcpf(1.f + ev), k3);                \
        float ai = qperm<0x00>(a);                                               \
        float af = qperm<0x55>(a);                                               \
        float ag = qperm<0xAA>(a);                                               \
        float ao = qperm<0xFF>(a);                                               \
        c = fmaf(af, c, ai * ag);                                                \
        float e2 = __expf(2.f * c);                                              \
        float th = fmaf(-2.f, __builtin_amdgcn_rcpf(1.f + e2), 1.f);             \
        float hnew = ao * th;                                                    \
        if (p == 0) {                                                            \
            (HDST)[hwr] = hnew;                                                  \
            if (AGH) st_agent((HOPTR), hnew); else *(HOPTR) = hnew;              \
        }                                                                        \
        bar_fast();                                                              \
    }

    for (int ch = 0; ch < NCH; ++ch) {
        const int n0 = ch * CHK;
        const int n1 = (n0 + CHK < NTOT) ? (n0 + CHK) : NTOT;   // even count
        if (WAIT) {
            if (tid == 0) {
                while (__hip_atomic_load(wflag + ch, __ATOMIC_RELAXED, __HIP_MEMORY_SCOPE_AGENT) == 0)
                    __builtin_amdgcn_s_sleep(1);
            }
            __syncthreads();
            __threadfence();   // acquire
        }
        const float* xb = X + (size_t)n0 * 512 + xoff;
        float* hop = Hout + (size_t)n0 * HH + j;
        float xc0 = AGX ? ld_agent(xb) : xb[0];
        float xc1 = AGX ? ld_agent(xb + 512) : xb[512];
        for (int n = n0; n < n1; n += 2) {
            float xp2 = 0.f, xp3 = 0.f;
            if (n + 2 < n1) {
                xp2 = AGX ? ld_agent(xb + 1024) : xb[1024];
                xp3 = AGX ? ld_agent(xb + 1536) : xb[1536];
            }
            REC_STEP(hb0s, hb1s, xc0, hop)
            REC_STEP(hb1s, hb0s, xc1, hop + HH)
            xc0 = xp2; xc1 = xp3;
            xb += 1024; hop += 2 * HH;
        }
        if (SIG) {
            __syncthreads();   // full drain: h stores visible before flag
            if (tid == 0)
                __hip_atomic_store(sflag + ch, 1, __ATOMIC_RELEASE, __HIP_MEMORY_SCOPE_AGENT);
        }
    }
#undef REC_STEP
}

// ---------------- layer-2 input projection worker (1024 thr: 512 rows x 2) -------
__device__ __forceinline__ void proj_work(
    const float* __restrict__ h1, const float* __restrict__ Wih,
    const float* __restrict__ bih, const float* __restrict__ bhh,
    float* __restrict__ X2, int* wflag, int* sflag)
{
    __shared__ float hl[CHK * HH];     // 32 KB
    const int tid = threadIdx.x;       // 0..1023
    const int r = tid & 511;           // W_ih1 row (gate-major)
    const int half = tid >> 9;         // n-tile half
    const float bsum = bih[r] + bhh[r];
    const int col = xcol(r);
    const float4* wr = reinterpret_cast<const float4*>(Wih + (size_t)r * HH);
    for (int ch = 0; ch < NCH; ++ch) {
        const int n0 = ch * CHK;
        const int cnt = (n0 + CHK < NTOT) ? CHK : (NTOT - n0);
        if (tid == 0) {
            while (__hip_atomic_load(wflag + ch, __ATOMIC_RELAXED, __HIP_MEMORY_SCOPE_AGENT) == 0)
                __builtin_amdgcn_s_sleep(1);
        }
        __syncthreads();
        __threadfence();
        for (int i = tid; i < cnt * HH; i += 1024)
            hl[i] = ld_agent(h1 + (size_t)n0 * HH + i);
        __syncthreads();
        for (int t0 = half * 16; t0 < cnt; t0 += 32) {
            float acc[16];
            #pragma unroll
            for (int i = 0; i < 16; ++i) acc[i] = bsum;
            for (int k4 = 0; k4 < HH / 4; ++k4) {
                float4 wv = wr[k4];
                #pragma unroll
                for (int i = 0; i < 16; ++i) {
                    const float* hh = &hl[(t0 + i) * HH + 4 * k4];
                    acc[i] += wv.x*hh[0] + wv.y*hh[1] + wv.z*hh[2] + wv.w*hh[3];
                }
            }
            int tl = cnt - t0; if (tl > 16) tl = 16;
            for (int i = 0; i < tl; ++i)
                st_agent(X2 + (size_t)(n0 + t0 + i) * 512 + col, acc[i]);
        }
        __syncthreads();   // drain stores
        if (tid == 0)
            __hip_atomic_store(sflag + ch, 1, __ATOMIC_RELEASE, __HIP_MEMORY_SCOPE_AGENT);
    }
}

// ---------------- 3-stage pipeline: L1 rec -> proj -> L2 rec ----------------
// 1024 threads = 16 waves/CU -> HW-forced VGPR cap 128; per-thread need ~100.
__global__ __launch_bounds__(1024, 4) void k_pipe(
    const float* __restrict__ X1, const float* __restrict__ w_hh0, float* __restrict__ h1,
    const float* __restrict__ w_ih1, const float* __restrict__ b_ih1, const float* __restrict__ b_hh1,
    float* __restrict__ X2, const float* __restrict__ w_hh1, float* __restrict__ out,
    int* flags1, int* flags2)
{
    if (blockIdx.x == 0)
        lstm_rec<false, true, false, true>(X1, w_hh0, h1, nullptr, flags1);
    else if (blockIdx.x == 1)
        proj_work(h1, w_ih1, b_ih1, b_hh1, X2, flags1, flags2);
    else
        lstm_rec<true, false, true, false>(X2, w_hh1, out, flags2, nullptr);
}

extern "C" void kernel_launch(void* const* d_in, const int* in_sizes, int n_in,
                              void* d_out, int out_size, void* d_ws, size_t ws_size,
                              hipStream_t stream) {
    const float* feat_svc = (const float*)d_in[0];
    const float* feat_pod = (const float*)d_in[1];
    const float* feat_node= (const float*)d_in[2];
    const float* w_svc = (const float*)d_in[3];
    const float* b_svc = (const float*)d_in[4];
    const float* w_in  = (const float*)d_in[5];
    const float* b_in  = (const float*)d_in[6];
    const float* w_ni  = (const float*)d_in[7];
    const float* b_ni  = (const float*)d_in[8];
    const float* lw_svc = (const float*)d_in[9];
    const float* lb_svc = (const float*)d_in[10];
    const float* lw_pod = (const float*)d_in[11];
    const float* lb_pod = (const float*)d_in[12];
    const float* lw_node= (const float*)d_in[13];
    const float* lb_node= (const float*)d_in[14];
    const float* w_ih0 = (const float*)d_in[15];
    const float* w_hh0 = (const float*)d_in[16];
    const float* b_ih0 = (const float*)d_in[17];
    const float* b_hh0 = (const float*)d_in[18];
    const float* w_ih1 = (const float*)d_in[19];
    const float* w_hh1 = (const float*)d_in[20];
    const float* b_ih1 = (const float*)d_in[21];
    const float* b_hh1 = (const float*)d_in[22];
    const int* eA_src = (const int*)d_in[23];   // svc -> svc
    const int* eA_dst = (const int*)d_in[24];
    const int* eB_src = (const int*)d_in[25];   // pod -> node
    const int* eB_dst = (const int*)d_in[26];
    const int* eC_src = (const int*)d_in[27];   // node -> pod
    const int* eC_dst = (const int*)d_in[28];

    float* ws = (float*)d_ws;
    // layout (4B units)
    float* ocA = ws + 0;        // 2000
    float* icA = ws + 2000;     // 2000
    float* ocB = ws + 4000;     // 8000 (pod out-deg)
    float* icB = ws + 12000;    // 1000 (node in-deg)
    float* ocC = ws + 13000;    // 1000 (node out-deg)
    float* icC = ws + 14000;    // 8000 (pod in-deg)
    int* curA = (int*)(ws + 22000);  // 2000
    int* curB = (int*)(ws + 24000);  // 1000
    int* curC = (int*)(ws + 25000);  // 8000
    int* offA = (int*)(ws + 33000);  // 2001
    int* offB = (int*)(ws + 35001);  // 1001
    int* offC = (int*)(ws + 36002);  // 8001
    int* sA   = (int*)(ws + 44003);  // 30000
    int* sB   = (int*)(ws + 74003);  // 24000
    int* sC   = (int*)(ws + 98003);  // 24000
    float* xseq = ws + 122003;       // 11000*32
    float* X1   = ws + 474003;       // 11000*512
    float* h1   = ws + 6106003;      // 11000*128
    int* flags1 = (int*)(ws + 7514003);   // NCH
    int* flags2 = flags1 + NCH;           // NCH
    float* X2   = X1;   // layer-2 proj overwrites X1 chunk-in-place (gated by flags1)

    // zero deg counts + cursors + pipeline flags
    hipMemsetAsync(d_ws, 0, 33000 * sizeof(float), stream);
    hipMemsetAsync(flags1, 0, 2 * NCH * sizeof(int), stream);

    k_count3<<<(ETOT + 255) / 256, 256, 0, stream>>>(
        eA_src, eA_dst, eB_src, eB_dst, eC_src, eC_dst,
        ocA, icA, ocB, icB, ocC, icC);

    k_scan<<<3, 256, 0, stream>>>(icA, NSVC, offA, icB, NNODE, offB, icC, NPOD, offC);

    k_scatter3<<<(ETOT + 255) / 256, 256, 0, stream>>>(
        eA_src, eA_dst, eB_src, eB_dst, eC_src, eC_dst,
        offA, curA, sA, offB, curB, sB, offC, curC, sC);

    // merged convs: A rows [0,2000), C rows [2000,10000), B rows [10000,11000)
    k_conv3<<<dim3(TT, YA16 + YC16 + YB16), 256, 0, stream>>>(
        feat_svc, feat_pod, feat_node,
        w_svc, b_svc, lw_svc, lb_svc,
        w_ni, b_ni, lw_pod, lb_pod,
        w_in, b_in, lw_node, lb_node,
        ocA, icA, offA, sA,
        ocC, icC, offC, sC,
        ocB, icB, offB, sB,
        xseq);

    // layer-1 input projection (parallel GEMM, permuted X layout)
    k_proj<<<(NTOT + 15) / 16, 256, 0, stream>>>(xseq, TT, w_ih0, b_ih0, b_hh0, X1, NTOT);

    // 3-stage pipelined LSTM: L1 recurrence -> L2 proj -> L2 recurrence
    k_pipe<<<3, 1024, 0, stream>>>(X1, w_hh0, h1, w_ih1, b_ih1, b_hh1,
                                   X2, w_hh1, (float*)d_out, flags1, flags2);
}

// Round 10
// 11033.076 us; speedup vs baseline: 1.5395x; 1.0007x over previous
//
#include <hip/hip_runtime.h>

#define NSVC 2000
#define NPOD 8000
#define NNODE 1000
#define NTOT 11000
#define TT 32
#define FF 64
#define HH 128
#define EA 30000
#define EB 24000
#define EC 24000
#define ETOT (EA + EB + EC)
#define CHK 64
#define NCH ((NTOT + CHK - 1) / CHK)   // 172 (all chunk lengths even)

// ---------------- agent-scope helpers (cross-XCD safe) ----------------
__device__ __forceinline__ float ld_agent(const float* p) {
    return __hip_atomic_load(p, __ATOMIC_RELAXED, __HIP_MEMORY_SCOPE_AGENT);
}
__device__ __forceinline__ void st_agent(float* p, float v) {
    __hip_atomic_store(p, v, __ATOMIC_RELAXED, __HIP_MEMORY_SCOPE_AGENT);
}
// barrier that does NOT drain vmcnt (keeps global loads/stores in flight)
__device__ __forceinline__ void bar_fast() {
    asm volatile("s_waitcnt lgkmcnt(0)" ::: "memory");
    __builtin_amdgcn_s_barrier();
}
// DPP quad_perm: xor1=0xB1 [1,0,3,2], xor2=0x4E [2,3,0,1], bcast q0..q3=0x00,0x55,0xAA,0xFF
template<int CTRL>
__device__ __forceinline__ float qperm(float x) {
    return __int_as_float(__builtin_amdgcn_mov_dpp(__float_as_int(x), CTRL, 0xF, 0xF, false));
}
// lane ^ 4 cross-lane (BitMode swizzle: and=0x1F, or=0, xor=4)
__device__ __forceinline__ float swz_xor4(float x) {
    return __int_as_float(__builtin_amdgcn_ds_swizzle(__float_as_int(x), 0x101F));
}
// opacity pin: make 4 float4s non-rematerializable (force VGPR residency)
#define PIN4(a, b, c, d)                                                        \
    asm volatile("" : "+v"((a).x), "+v"((a).y), "+v"((a).z), "+v"((a).w),       \
                      "+v"((b).x), "+v"((b).y), "+v"((b).z), "+v"((b).w),       \
                      "+v"((c).x), "+v"((c).y), "+v"((c).z), "+v"((c).w),       \
                      "+v"((d).x), "+v"((d).y), "+v"((d).z), "+v"((d).w))

// ---------------- merged degree counting ----------------
__global__ void k_count3(const int* __restrict__ sA, const int* __restrict__ dA,
                         const int* __restrict__ sB, const int* __restrict__ dB,
                         const int* __restrict__ sC, const int* __restrict__ dC,
                         float* ocA, float* icA, float* ocB, float* icB,
                         float* ocC, float* icC) {
    int e = blockIdx.x * 256 + threadIdx.x;
    if (e < EA) {
        atomicAdd(ocA + sA[e], 1.f); atomicAdd(icA + dA[e], 1.f);
    } else if (e < EA + EB) {
        int i = e - EA;
        atomicAdd(ocB + sB[i], 1.f); atomicAdd(icB + dB[i], 1.f);
    } else if (e < ETOT) {
        int i = e - EA - EB;
        atomicAdd(ocC + sC[i], 1.f); atomicAdd(icC + dC[i], 1.f);
    }
}

// ---------------- prefix scan (3 graphs, one block each) ----------------
__global__ void k_scan(const float* cA, int nA, int* oA,
                       const float* cB, int nB, int* oB,
                       const float* cC, int nC, int* oC) {
    const float* c; int n; int* o;
    if (blockIdx.x == 0)      { c = cA; n = nA; o = oA; }
    else if (blockIdx.x == 1) { c = cB; n = nB; o = oB; }
    else                      { c = cC; n = nC; o = oC; }
    __shared__ int s[256];
    __shared__ int carry;
    int tid = threadIdx.x;
    if (tid == 0) { carry = 0; o[0] = 0; }
    __syncthreads();
    for (int base = 0; base < n; base += 256) {
        int idx = base + tid;
        int v = (idx < n) ? (int)c[idx] : 0;
        s[tid] = v;
        __syncthreads();
        for (int d = 1; d < 256; d <<= 1) {
            int t = (tid >= d) ? s[tid - d] : 0;
            __syncthreads();
            s[tid] += t;
            __syncthreads();
        }
        if (idx < n) o[idx + 1] = carry + s[tid];
        __syncthreads();
        if (tid == 255) carry += s[255];
        __syncthreads();
    }
}

// ---------------- merged CSR scatter ----------------
__global__ void k_scatter3(const int* __restrict__ sA, const int* __restrict__ dA,
                           const int* __restrict__ sB, const int* __restrict__ dB,
                           const int* __restrict__ sC, const int* __restrict__ dC,
                           const int* offA, int* curA, int* csrA,
                           const int* offB, int* curB, int* csrB,
                           const int* offC, int* curC, int* csrC) {
    int e = blockIdx.x * 256 + threadIdx.x;
    if (e < EA) {
        int d = dA[e]; int p = atomicAdd(curA + d, 1); csrA[offA[d] + p] = sA[e];
    } else if (e < EA + EB) {
        int i = e - EA;
        int d = dB[i]; int p = atomicAdd(curB + d, 1); csrB[offB[d] + p] = sB[i];
    } else if (e < ETOT) {
        int i = e - EA - EB;
        int d = dC[i]; int p = atomicAdd(curC + d, 1); csrC[offC[d] + p] = sC[i];
    }
}

// ---------------- fused conv (3 graphs merged, 16 dst/block) ----------------
#define YA16 ((NSVC + 15) / 16)    // 125
#define YC16 ((NPOD + 15) / 16)    // 500
#define YB16 ((NNODE + 15) / 16)   // 63
__global__ __launch_bounds__(256) void k_conv3(
    const float* __restrict__ feat_svc, const float* __restrict__ feat_pod,
    const float* __restrict__ feat_node,
    const float* __restrict__ w_svc, const float* __restrict__ b_svc,
    const float* __restrict__ lw_svc, const float* __restrict__ lb_svc,
    const float* __restrict__ w_ni, const float* __restrict__ b_ni,
    const float* __restrict__ lw_pod, const float* __restrict__ lb_pod,
    const float* __restrict__ w_in, const float* __restrict__ b_in,
    const float* __restrict__ lw_node, const float* __restrict__ lb_node,
    const float* ocA, const float* icA, const int* offA, const int* csrA,
    const float* ocC, const float* icC, const int* offC, const int* csrC,
    const float* ocB, const float* icB, const int* offB, const int* csrB,
    float* __restrict__ xseq)
{
    __shared__ float wl[FF * HH];
    __shared__ float bl[HH], lwl[HH];
    __shared__ float accs[4][FF];
    const int t = blockIdx.x;
    const int tid = threadIdx.x;
    int yb = blockIdx.y;
    const float *x, *w, *b, *lw, *lb, *oc, *ic; const int *off, *csr;
    int Ndst, rowofs;
    if (yb < YA16) {
        x = feat_svc; w = w_svc; b = b_svc; lw = lw_svc; lb = lb_svc;
        oc = ocA; ic = icA; off = offA; csr = csrA; Ndst = NSVC; rowofs = 0;
    } else if (yb < YA16 + YC16) {
        yb -= YA16;
        x = feat_node; w = w_ni; b = b_ni; lw = lw_pod; lb = lb_pod;
        oc = ocC; ic = icC; off = offC; csr = csrC; Ndst = NPOD; rowofs = NSVC;
    } else {
        yb -= YA16 + YC16;
        x = feat_pod; w = w_in; b = b_in; lw = lw_node; lb = lb_node;
        oc = ocB; ic = icB; off = offB; csr = csrB; Ndst = NNODE; rowofs = NSVC + NPOD;
    }
    for (int i = tid; i < FF * HH; i += 256) wl[i] = w[t * FF * HH + i];
    if (tid < HH) { bl[tid] = b[t * HH + tid]; lwl[tid] = lw[t * HH + tid]; }
    const int wv = tid >> 6, lane = tid & 63;
    __syncthreads();
    for (int sub = 0; sub < 4; ++sub) {
        const int dstn = yb * 16 + sub * 4 + wv;
        if (dstn < Ndst) {
            float a = 0.f;
            const int e0 = off[dstn], e1 = off[dstn + 1];
            const float* xb = x + (size_t)t * FF + lane;
            float xsP = 0.f, ocP = 1.f;
            if (e0 < e1) {
                int s0 = csr[e0];
                xsP = xb[(size_t)s0 * (TT * FF)]; ocP = oc[s0];
            }
            for (int i = e0; i < e1; ++i) {
                float xs = xsP, od = ocP;
                if (i + 1 < e1) {
                    int s2 = csr[i + 1];
                    xsP = xb[(size_t)s2 * (TT * FF)]; ocP = oc[s2];
                }
                a = fmaf(xs, rsqrtf(fmaxf(od, 1.f)), a);
            }
            a *= rsqrtf(fmaxf(ic[dstn], 1.f));
            accs[wv][lane] = a;     // wave-local: write then read by same wave
            float h0 = bl[lane], h1v = bl[64 + lane];
            #pragma unroll
            for (int f = 0; f < FF; ++f) {
                float af = accs[wv][f];
                h0  = fmaf(af, wl[f * HH + lane], h0);
                h1v = fmaf(af, wl[f * HH + 64 + lane], h1v);
            }
            h0  = (h0  >= 0.f) ? h0  : 0.01f * h0;
            h1v = (h1v >= 0.f) ? h1v : 0.01f * h1v;
            float p = h0 * lwl[lane] + h1v * lwl[64 + lane];
            #pragma unroll
            for (int o2 = 32; o2 >= 1; o2 >>= 1) p += __shfl_down(p, o2);
            if (lane == 0) xseq[(size_t)(rowofs + dstn) * TT + t] = p + lb[t];
        }
    }
}

// X layout: gate-major row r = g*128+j stored at column (j<<2)|g.
__device__ __forceinline__ int xcol(int r) { return ((r & 127) << 2) | (r >> 7); }

// ---------------- input projection (layer 1): X = xin @ wih^T + (bih + bhh) --------
__global__ __launch_bounds__(256) void k_proj(
    const float* __restrict__ xin, int K,      // [N, K]
    const float* __restrict__ wih,             // [512, K]
    const float* __restrict__ bih, const float* __restrict__ bhh,
    float* __restrict__ Xout, int N)           // [N, 512] permuted cols
{
    __shared__ float xt[16 * 128];
    int n0 = blockIdx.x * 16, tid = threadIdx.x;
    for (int i = tid; i < 16 * K; i += 256) {
        int nn = i / K, kk = i - nn * K;
        int n = n0 + nn;
        xt[i] = (n < N) ? xin[(size_t)n * K + kk] : 0.f;
    }
    __syncthreads();
    float acc0[16], acc1[16];
    #pragma unroll
    for (int i = 0; i < 16; ++i) { acc0[i] = 0.f; acc1[i] = 0.f; }
    int r0 = tid, r1 = tid + 256;
    for (int k = 0; k < K; ++k) {
        float w0 = wih[(size_t)r0 * K + k];
        float w1 = wih[(size_t)r1 * K + k];
        #pragma unroll
        for (int i = 0; i < 16; ++i) {
            float xv = xt[i * K + k];
            acc0[i] = fmaf(xv, w0, acc0[i]);
            acc1[i] = fmaf(xv, w1, acc1[i]);
        }
    }
    float b0 = bih[r0] + bhh[r0], b1 = bih[r1] + bhh[r1];
    int c0 = xcol(r0), c1 = xcol(r1);
    for (int i = 0; i < 16; ++i) {
        int n = n0 + i;
        if (n < N) {
            Xout[(size_t)n * 512 + c0] = acc0[i] + b0;
            Xout[(size_t)n * 512 + c1] = acc1[i] + b1;
        }
    }
}

// ---------------- sequential LSTM recurrence (1024 threads = 16 waves) ------------
// thread = (j,p): unit j = tid>>3, k-slice p = tid&7 (16 k each). 64 weight
// floats/thread as 16 named float4s, PINNED via empty asm (+v) so the compiler
// cannot sink/rematerialize the loads into the loop (R9 post-mortem: it was
// re-streaming 256 KB/step of Whh from L2 — the ~1 µs/step wall of R2-R9).
template<bool AGX, bool AGH, bool WAIT, bool SIG>
__device__ __forceinline__ void lstm_rec(
    const float* __restrict__ X, const float* __restrict__ Whh,
    float* __restrict__ Hout, int* wflag, int* sflag)
{
    __shared__ __align__(16) float hb0s[8 * 20], hb1s[8 * 20];
    const int tid = threadIdx.x;           // 0..1023
    const int j = tid >> 3, p = tid & 7;
    const int g4 = p & 3;
    // weights: gate g row (g*128+j), k-slice [16p, 16p+16) -> 4 float4 per gate
    const float* bj = Whh + (size_t)j * HH + p * 16;
    const float4* r0 = reinterpret_cast<const float4*>(bj);
    const float4* r1 = reinterpret_cast<const float4*>(bj + 128 * HH);
    const float4* r2 = reinterpret_cast<const float4*>(bj + 256 * HH);
    const float4* r3 = reinterpret_cast<const float4*>(bj + 384 * HH);
    float4 w00 = r0[0], w01 = r0[1], w02 = r0[2], w03 = r0[3];
    float4 w10 = r1[0], w11 = r1[1], w12 = r1[2], w13 = r1[3];
    float4 w20 = r2[0], w21 = r2[1], w22 = r2[2], w23 = r2[3];
    float4 w30 = r3[0], w31 = r3[1], w32 = r3[2], w33 = r3[3];
    // force residency: values become opaque, loads cannot be sunk into the loop
    PIN4(w00, w01, w02, w03);
    PIN4(w10, w11, w12, w13);
    PIN4(w20, w21, w22, w23);
    PIN4(w30, w31, w32, w33);
    if (tid < 160) hb0s[tid] = 0.f;
    // sigmoid (g4=0,1,3): a = 1/(1+e^-s); tanh (g4=2): a = 1 - 2/(1+e^2s)
    const float k1 = (g4 == 2) ? -2.f : 1.f;
    const float k2 = (g4 == 2) ? 2.f : -1.f;
    const float k3 = (g4 == 2) ? 1.f : 0.f;
    const bool pa = (p & 1) != 0, pb = (p & 2) != 0;
    const int hwr = ((j >> 4) * 20) + (j & 15);   // write slot for unit j
    const int hrd = p * 20;                       // read base for slice p
    const int xoff = (j << 2) | g4;               // X column for (unit j, gate g4)
    float c = 0.f;   // identical across each 8-lane group
    __syncthreads();

#define REC_STEP(HSRC, HDST, XC, HOPTR)                                          \
    {                                                                            \
        const float4* hr = reinterpret_cast<const float4*>((HSRC) + hrd);        \
        float4 hA = hr[0], hB = hr[1], hC = hr[2], hD = hr[3];                   \
        float s0 = w00.x * hA.x;                                                 \
        s0 = fmaf(w00.y, hA.y, s0); s0 = fmaf(w00.z, hA.z, s0);                  \
        s0 = fmaf(w00.w, hA.w, s0); s0 = fmaf(w01.x, hB.x, s0);                  \
        s0 = fmaf(w01.y, hB.y, s0); s0 = fmaf(w01.z, hB.z, s0);                  \
        s0 = fmaf(w01.w, hB.w, s0); s0 = fmaf(w02.x, hC.x, s0);                  \
        s0 = fmaf(w02.y, hC.y, s0); s0 = fmaf(w02.z, hC.z, s0);                  \
        s0 = fmaf(w02.w, hC.w, s0); s0 = fmaf(w03.x, hD.x, s0);                  \
        s0 = fmaf(w03.y, hD.y, s0); s0 = fmaf(w03.z, hD.z, s0);                  \
        s0 = fmaf(w03.w, hD.w, s0);                                              \
        float s1 = w10.x * hA.x;                                                 \
        s1 = fmaf(w10.y, hA.y, s1); s1 = fmaf(w10.z, hA.z, s1);                  \
        s1 = fmaf(w10.w, hA.w, s1); s1 = fmaf(w11.x, hB.x, s1);                  \
        s1 = fmaf(w11.y, hB.y, s1); s1 = fmaf(w11.z, hB.z, s1);                  \
        s1 = fmaf(w11.w, hB.w, s1); s1 = fmaf(w12.x, hC.x, s1);                  \
        s1 = fmaf(w12.y, hC.y, s1); s1 = fmaf(w12.z, hC.z, s1);                  \
        s1 = fmaf(w12.w, hC.w, s1); s1 = fmaf(w13.x, hD.x, s1);                  \
        s1 = fmaf(w13.y, hD.y, s1); s1 = fmaf(w13.z, hD.z, s1);                  \
        s1 = fmaf(w13.w, hD.w, s1);                                              \
        float s2 = w20.x * hA.x;                                                 \
        s2 = fmaf(w20.y, hA.y, s2); s2 = fmaf(w20.z, hA.z, s2);                  \
        s2 = fmaf(w20.w, hA.w, s2); s2 = fmaf(w21.x, hB.x, s2);                  \
        s2 = fmaf(w21.y, hB.y, s2); s2 = fmaf(w21.z, hB.z, s2);                  \
        s2 = fmaf(w21.w, hB.w, s2); s2 = fmaf(w22.x, hC.x, s2);                  \
        s2 = fmaf(w22.y, hC.y, s2); s2 = fmaf(w22.z, hC.z, s2);                  \
        s2 = fmaf(w22.w, hC.w, s2); s2 = fmaf(w23.x, hD.x, s2);                  \
        s2 = fmaf(w23.y, hD.y, s2); s2 = fmaf(w23.z, hD.z, s2);                  \
        s2 = fmaf(w23.w, hD.w, s2);                                              \
        float s3 = w30.x * hA.x;                                                 \
        s3 = fmaf(w30.y, hA.y, s3); s3 = fmaf(w30.z, hA.z, s3);                  \
        s3 = fmaf(w30.w, hA.w, s3); s3 = fmaf(w31.x, hB.x, s3);                  \
        s3 = fmaf(w31.y, hB.y, s3); s3 = fmaf(w31.z, hB.z, s3);                  \
        s3 = fmaf(w31.w, hB.w, s3); s3 = fmaf(w32.x, hC.x, s3);                  \
        s3 = fmaf(w32.y, hC.y, s3); s3 = fmaf(w32.z, hC.z, s3);                  \
        s3 = fmaf(w32.w, hC.w, s3); s3 = fmaf(w33.x, hD.x, s3);                  \
        s3 = fmaf(w33.y, hD.y, s3); s3 = fmaf(w33.z, hD.z, s3);                  \
        s3 = fmaf(w33.w, hD.w, s3);                                              \
        /* quad reduce-scatter: lane ends with gate g4 over its quad's 64 k */   \
        float zA = pa ? s0 : s1;                                                 \
        float u  = (pa ? s1 : s0) + qperm<0xB1>(zA);                             \
        float zB = pa ? s2 : s3;                                                 \
        float v  = (pa ? s3 : s2) + qperm<0xB1>(zB);                             \
        float zC = pb ? u : v;                                                   \
        float sf = (pb ? v : u) + qperm<0x4E>(zC);                               \
        /* xor4: sum the two 64-k halves (lanes p and p^4 hold same gate) */     \
        sf += swz_xor4(sf);                                                      \
        sf += (XC);                                                              \
        float ev = __expf(k2 * sf);                                              \
        float a  = fmaf(k1, __builtin_amdgcn_rcpf(1.f + ev), k3);                \
        float ai = qperm<0x00>(a);                                               \
        float af = qperm<0x55>(a);                                               \
        float ag = qperm<0xAA>(a);                                               \
        float ao = qperm<0xFF>(a);                                               \
        c = fmaf(af, c, ai * ag);                                                \
        float e2 = __expf(2.f * c);                                              \
        float th = fmaf(-2.f, __builtin_amdgcn_rcpf(1.f + e2), 1.f);             \
        float hnew = ao * th;                                                    \
        if (p == 0) {                                                            \
            (HDST)[hwr] = hnew;                                                  \
            if (AGH) st_agent((HOPTR), hnew); else *(HOPTR) = hnew;              \
        }                                                                        \
        bar_fast();                                                              \
    }

    for (int ch = 0; ch < NCH; ++ch) {
        const int n0 = ch * CHK;
        const int n1 = (n0 + CHK < NTOT) ? (n0 + CHK) : NTOT;   // even count
        if (WAIT) {
            if (tid == 0) {
                while (__hip_atomic_load(wflag + ch, __ATOMIC_RELAXED, __HIP_MEMORY_SCOPE_AGENT) == 0)
                    __builtin_amdgcn_s_sleep(1);
            }
            __syncthreads();
            __threadfence();   // acquire
        }
        const float* xb = X + (size_t)n0 * 512 + xoff;
        float* hop = Hout + (size_t)n0 * HH + j;
        float xc0 = AGX ? ld_agent(xb) : xb[0];
        float xc1 = AGX ? ld_agent(xb + 512) : xb[512];
        for (int n = n0; n < n1; n += 2) {
            float xp2 = 0.f, xp3 = 0.f;
            if (n + 2 < n1) {
                xp2 = AGX ? ld_agent(xb + 1024) : xb[1024];
                xp3 = AGX ? ld_agent(xb + 1536) : xb[1536];
            }
            REC_STEP(hb0s, hb1s, xc0, hop)
            REC_STEP(hb1s, hb0s, xc1, hop + HH)
            xc0 = xp2; xc1 = xp3;
            xb += 1024; hop += 2 * HH;
        }
        if (SIG) {
            __syncthreads();   // full drain: h stores visible before flag
            if (tid == 0)
                __hip_atomic_store(sflag + ch, 1, __ATOMIC_RELEASE, __HIP_MEMORY_SCOPE_AGENT);
        }
    }
#undef REC_STEP
}

// ---------------- layer-2 input projection worker (1024 thr: 512 rows x 2) -------
__device__ __forceinline__ void proj_work(
    const float* __restrict__ h1, const float* __restrict__ Wih,
    const float* __restrict__ bih, const float* __restrict__ bhh,
    float* __restrict__ X2, int* wflag, int* sflag)
{
    __shared__ float hl[CHK * HH];     // 32 KB
    const int tid = threadIdx.x;       // 0..1023
    const int r = tid & 511;           // W_ih1 row (gate-major)
    const int half = tid >> 9;         // n-tile half
    const float bsum = bih[r] + bhh[r];
    const int col = xcol(r);
    const float4* wr = reinterpret_cast<const float4*>(Wih + (size_t)r * HH);
    for (int ch = 0; ch < NCH; ++ch) {
        const int n0 = ch * CHK;
        const int cnt = (n0 + CHK < NTOT) ? CHK : (NTOT - n0);
        if (tid == 0) {
            while (__hip_atomic_load(wflag + ch, __ATOMIC_RELAXED, __HIP_MEMORY_SCOPE_AGENT) == 0)
                __builtin_amdgcn_s_sleep(1);
        }
        __syncthreads();
        __threadfence();
        for (int i = tid; i < cnt * HH; i += 1024)
            hl[i] = ld_agent(h1 + (size_t)n0 * HH + i);
        __syncthreads();
        for (int t0 = half * 16; t0 < cnt; t0 += 32) {
            float acc[16];
            #pragma unroll
            for (int i = 0; i < 16; ++i) acc[i] = bsum;
            for (int k4 = 0; k4 < HH / 4; ++k4) {
                float4 wv = wr[k4];
                #pragma unroll
                for (int i = 0; i < 16; ++i) {
                    const float* hh = &hl[(t0 + i) * HH + 4 * k4];
                    acc[i] += wv.x*hh[0] + wv.y*hh[1] + wv.z*hh[2] + wv.w*hh[3];
                }
            }
            int tl = cnt - t0; if (tl > 16) tl = 16;
            for (int i = 0; i < tl; ++i)
                st_agent(X2 + (size_t)(n0 + t0 + i) * 512 + col, acc[i]);
        }
        __syncthreads();   // drain stores
        if (tid == 0)
            __hip_atomic_store(sflag + ch, 1, __ATOMIC_RELEASE, __HIP_MEMORY_SCOPE_AGENT);
    }
}

// ---------------- 3-stage pipeline: L1 rec -> proj -> L2 rec ----------------
// 1024 threads = 16 waves/CU -> VGPR cap 128; per-thread need ~110 (w pinned).
__global__ __launch_bounds__(1024, 4) void k_pipe(
    const float* __restrict__ X1, const float* __restrict__ w_hh0, float* __restrict__ h1,
    const float* __restrict__ w_ih1, const float* __restrict__ b_ih1, const float* __restrict__ b_hh1,
    float* __restrict__ X2, const float* __restrict__ w_hh1, float* __restrict__ out,
    int* flags1, int* flags2)
{
    if (blockIdx.x == 0)
        lstm_rec<false, true, false, true>(X1, w_hh0, h1, nullptr, flags1);
    else if (blockIdx.x == 1)
        proj_work(h1, w_ih1, b_ih1, b_hh1, X2, flags1, flags2);
    else
        lstm_rec<true, false, true, false>(X2, w_hh1, out, flags2, nullptr);
}

extern "C" void kernel_launch(void* const* d_in, const int* in_sizes, int n_in,
                              void* d_out, int out_size, void* d_ws, size_t ws_size,
                              hipStream_t stream) {
    const float* feat_svc = (const float*)d_in[0];
    const float* feat_pod = (const float*)d_in[1];
    const float* feat_node= (const float*)d_in[2];
    const float* w_svc = (const float*)d_in[3];
    const float* b_svc = (const float*)d_in[4];
    const float* w_in  = (const float*)d_in[5];
    const float* b_in  = (const float*)d_in[6];
    const float* w_ni  = (const float*)d_in[7];
    const float* b_ni  = (const float*)d_in[8];
    const float* lw_svc = (const float*)d_in[9];
    const float* lb_svc = (const float*)d_in[10];
    const float* lw_pod = (const float*)d_in[11];
    const float* lb_pod = (const float*)d_in[12];
    const float* lw_node= (const float*)d_in[13];
    const float* lb_node= (const float*)d_in[14];
    const float* w_ih0 = (const float*)d_in[15];
    const float* w_hh0 = (const float*)d_in[16];
    const float* b_ih0 = (const float*)d_in[17];
    const float* b_hh0 = (const float*)d_in[18];
    const float* w_ih1 = (const float*)d_in[19];
    const float* w_hh1 = (const float*)d_in[20];
    const float* b_ih1 = (const float*)d_in[21];
    const float* b_hh1 = (const float*)d_in[22];
    const int* eA_src = (const int*)d_in[23];   // svc -> svc
    const int* eA_dst = (const int*)d_in[24];
    const int* eB_src = (const int*)d_in[25];   // pod -> node
    const int* eB_dst = (const int*)d_in[26];
    const int* eC_src = (const int*)d_in[27];   // node -> pod
    const int* eC_dst = (const int*)d_in[28];

    float* ws = (float*)d_ws;
    // layout (4B units)
    float* ocA = ws + 0;        // 2000
    float* icA = ws + 2000;     // 2000
    float* ocB = ws + 4000;     // 8000 (pod out-deg)
    float* icB = ws + 12000;    // 1000 (node in-deg)
    float* ocC = ws + 13000;    // 1000 (node out-deg)
    float* icC = ws + 14000;    // 8000 (pod in-deg)
    int* curA = (int*)(ws + 22000);  // 2000
    int* curB = (int*)(ws + 24000);  // 1000
    int* curC = (int*)(ws + 25000);  // 8000
    int* offA = (int*)(ws + 33000);  // 2001
    int* offB = (int*)(ws + 35001);  // 1001
    int* offC = (int*)(ws + 36002);  // 8001
    int* sA   = (int*)(ws + 44003);  // 30000
    int* sB   = (int*)(ws + 74003);  // 24000
    int* sC   = (int*)(ws + 98003);  // 24000
    float* xseq = ws + 122003;       // 11000*32
    float* X1   = ws + 474003;       // 11000*512
    float* h1   = ws + 6106003;      // 11000*128
    int* flags1 = (int*)(ws + 7514003);   // NCH
    int* flags2 = flags1 + NCH;           // NCH
    float* X2   = X1;   // layer-2 proj overwrites X1 chunk-in-place (gated by flags1)

    // zero deg counts + cursors + pipeline flags
    hipMemsetAsync(d_ws, 0, 33000 * sizeof(float), stream);
    hipMemsetAsync(flags1, 0, 2 * NCH * sizeof(int), stream);

    k_count3<<<(ETOT + 255) / 256, 256, 0, stream>>>(
        eA_src, eA_dst, eB_src, eB_dst, eC_src, eC_dst,
        ocA, icA, ocB, icB, ocC, icC);

    k_scan<<<3, 256, 0, stream>>>(icA, NSVC, offA, icB, NNODE, offB, icC, NPOD, offC);

    k_scatter3<<<(ETOT + 255) / 256, 256, 0, stream>>>(
        eA_src, eA_dst, eB_src, eB_dst, eC_src, eC_dst,
        offA, curA, sA, offB, curB, sB, offC, curC, sC);

    // merged convs: A rows [0,2000), C rows [2000,10000), B rows [10000,11000)
    k_conv3<<<dim3(TT, YA16 + YC16 + YB16), 256, 0, stream>>>(
        feat_svc, feat_pod, feat_node,
        w_svc, b_svc, lw_svc, lb_svc,
        w_ni, b_ni, lw_pod, lb_pod,
        w_in, b_in, lw_node, lb_node,
        ocA, icA, offA, sA,
        ocC, icC, offC, sC,
        ocB, icB, offB, sB,
        xseq);

    // layer-1 input projection (parallel GEMM, permuted X layout)
    k_proj<<<(NTOT + 15) / 16, 256, 0, stream>>>(xseq, TT, w_ih0, b_ih0, b_hh0, X1, NTOT);

    // 3-stage pipelined LSTM: L1 recurrence -> L2 proj -> L2 recurrence
    k_pipe<<<3, 1024, 0, stream>>>(X1, w_hh0, h1, w_ih1, b_ih1, b_hh1,
                                   X2, w_hh1, (float*)d_out, flags1, flags2);
}